// Round 5
// baseline (3632.993 us; speedup 1.0000x reference)
//
#include <hip/hip_runtime.h>
#include <hip/hip_bf16.h>
#include <stdint.h>

typedef unsigned long long u64;
typedef unsigned int u32;
typedef unsigned short u16;
typedef __attribute__((ext_vector_type(8))) short short8;
typedef __attribute__((ext_vector_type(16))) float float16;

#define NQ 2048
#define NT 65536
#define DIM 512
#define KNN 32
#define NC 100
#define NS 32               // slices (both paths), cand[q][slice][k]

// ---- fallback (R2) params ----
#define QT 32
#define SLICE (NT / NS)     // 2048
#define TT 256
#define KK 16
#define FCAP 32

// ---- prepass params (fp32, trains 0..2047 subsample) ----
#define PQT 32
#define PTT 256
#define PSLICE 512
#define NTPRE 2048

// ---- fused-mfma fallback params (R4, proven) ----
#define MQT 128             // queries per block
#define MTT 128             // trains per chunk
#define MBK 32              // k per stage
#define MSLICE 2048         // trains per block = SLICE
#define SCAP 16             // per-query candidate buffer per pass
#define NTILES 256          // (MSLICE/MTT) * (DIM/MBK)

// ---- split-path params (R5) ----
#define QSEL 32             // queries per select block

// ---------------- row-norm kernel ----------------
__global__ void norm_kernel(const float* __restrict__ X, float* __restrict__ out, int nrows) {
    int row = blockIdx.x * 4 + (threadIdx.x >> 6);
    int lane = threadIdx.x & 63;
    if (row >= nrows) return;
    const float4* p = (const float4*)(X + (size_t)row * DIM);
    float4 a = p[lane];
    float4 b = p[lane + 64];
    float s = a.x*a.x + a.y*a.y + a.z*a.z + a.w*a.w
            + b.x*b.x + b.y*b.y + b.z*b.z + b.w*b.w;
    #pragma unroll
    for (int off = 32; off > 0; off >>= 1) s += __shfl_down(s, off, 64);
    if (lane == 0) out[row] = s;
}

// ---------------- bf16 hi/lo split ----------------
__global__ void split_kernel(const float* __restrict__ X, u16* __restrict__ H,
                             u16* __restrict__ L, int n4) {
    int i = blockIdx.x * 256 + threadIdx.x;
    if (i >= n4) return;
    float4 v = ((const float4*)X)[i];
    float f[4] = {v.x, v.y, v.z, v.w};
    u16 hh[4], ll[4];
    #pragma unroll
    for (int j = 0; j < 4; ++j) {
        union { __hip_bfloat16 b; u16 u; } cv;
        cv.b = __float2bfloat16(f[j]);
        hh[j] = cv.u;
        float hf = __bfloat162float(cv.b);
        cv.b = __float2bfloat16(f[j] - hf);
        ll[j] = cv.u;
    }
    ((ushort4*)H)[i] = make_ushort4(hh[0], hh[1], hh[2], hh[3]);
    ((ushort4*)L)[i] = make_ushort4(ll[0], ll[1], ll[2], ll[3]);
}

// ---------------- prepass: exact 32nd-smallest distance over trains 0..2047 ----------------
// grid: (NQ/PQT=64, NTPRE/PSLICE=4). seed[q] = min over blocks of (32nd-smallest d2 bits).
// Subset property: 32nd-smallest over ANY train subset >= global 32nd -> valid filter UB.
__launch_bounds__(256, 2)
__global__ void knn_prepass(const float* __restrict__ Xq, const float* __restrict__ Xt,
                            const float* __restrict__ q2, const float* __restrict__ t2,
                            u32* __restrict__ seed) {
    __shared__ float sQ[KK][PQT];          // 2 KB
    __shared__ float sT[KK][PTT];          // 16 KB
    __shared__ float sD[PQT][PTT + 1];     // 32.1 KB (padded rows)
    __shared__ u32 topk[PQT][KNN + 1];     // 4.2 KB (dist bits only)

    const int tid = threadIdx.x;
    const int q0 = blockIdx.x * PQT;
    const int t0p = blockIdx.y * PSLICE;
    const int tq4 = (tid >> 5) * 4;
    const int tt4 = (tid & 31) * 4;
    const int pg = tid & 63;
    const int kg = tid >> 6;
    const int qp = tid & 31;
    const int kq = tid >> 5;

    for (int i = tid; i < PQT * (KNN + 1); i += 256) ((u32*)topk)[i] = 0xFFFFFFFFu;
    u32 kth = 0xFFFFFFFFu;   // register cache (selection threads)

    float qq[4];
    #pragma unroll
    for (int i = 0; i < 4; ++i) qq[i] = q2[q0 + tq4 + i];

    #pragma unroll 1
    for (int chunk = 0; chunk < PSLICE / PTT; ++chunk) {
        const int tbase = t0p + chunk * PTT;
        float acc[4][8];
        #pragma unroll
        for (int i = 0; i < 4; ++i)
            #pragma unroll
            for (int j = 0; j < 8; ++j) acc[i][j] = 0.f;

        #pragma unroll 1
        for (int k0 = 0; k0 < DIM; k0 += KK) {
            __syncthreads();   // protects sQ/sT and previous selection's sD reads
            {
                const float* Tp = Xt + (size_t)(tbase + pg * 4) * DIM + k0 + kg * 4;
                float4 r0 = *(const float4*)(Tp);
                float4 r1 = *(const float4*)(Tp + DIM);
                float4 r2 = *(const float4*)(Tp + 2 * DIM);
                float4 r3 = *(const float4*)(Tp + 3 * DIM);
                *(float4*)&sT[kg * 4 + 0][pg * 4] = make_float4(r0.x, r1.x, r2.x, r3.x);
                *(float4*)&sT[kg * 4 + 1][pg * 4] = make_float4(r0.y, r1.y, r2.y, r3.y);
                *(float4*)&sT[kg * 4 + 2][pg * 4] = make_float4(r0.z, r1.z, r2.z, r3.z);
                *(float4*)&sT[kg * 4 + 3][pg * 4] = make_float4(r0.w, r1.w, r2.w, r3.w);
            }
            {
                float2 v = *(const float2*)(Xq + (size_t)(q0 + qp) * DIM + k0 + kq * 2);
                sQ[kq * 2 + 0][qp] = v.x;
                sQ[kq * 2 + 1][qp] = v.y;
            }
            __syncthreads();
            #pragma unroll
            for (int k = 0; k < KK; ++k) {
                float4 qv = *(const float4*)&sQ[k][tq4];
                float4 ta = *(const float4*)&sT[k][tt4];
                float4 tb = *(const float4*)&sT[k][128 + tt4];
                float qa[4] = {qv.x, qv.y, qv.z, qv.w};
                float tv[8] = {ta.x, ta.y, ta.z, ta.w, tb.x, tb.y, tb.z, tb.w};
                #pragma unroll
                for (int i = 0; i < 4; ++i)
                    #pragma unroll
                    for (int j = 0; j < 8; ++j)
                        acc[i][j] = fmaf(qa[i], tv[j], acc[i][j]);
            }
        }

        #pragma unroll
        for (int i = 0; i < 4; ++i)
            #pragma unroll
            for (int j = 0; j < 8; ++j) {
                int t = (j < 4) ? (tt4 + j) : (128 + tt4 + (j - 4));
                sD[tq4 + i][t] = fmaxf((qq[i] - 2.f * acc[i][j]) + t2[tbase + t], 0.f);
            }
        __syncthreads();

        // serial scan selection; flood here is small (512 trains) and local
        if (tid < PQT) {
            for (int t = 0; t < PTT; ++t) {
                u32 d = __float_as_uint(sD[tid][t]);
                if (d < kth) {
                    int p = KNN - 1;
                    while (p > 0 && topk[tid][p - 1] > d) {
                        topk[tid][p] = topk[tid][p - 1];
                        --p;
                    }
                    topk[tid][p] = d;
                    kth = topk[tid][KNN - 1];
                }
            }
        }
        // next chunk's first barrier orders selection before sD is overwritten
    }
    if (tid < PQT) atomicMin(&seed[q0 + tid], kth);
}

// ---------------- async global->LDS 16B ----------------
__device__ __forceinline__ void gld16(const void* g, void* l) {
    __builtin_amdgcn_global_load_lds(
        (const __attribute__((address_space(1))) u32*)g,
        (__attribute__((address_space(3))) u32*)l, 16, 0, 0);
}

// ================== R5 split path: pure GEMM -> D slice, then select ==================

// ---------------- gemm_dist: m97-style 128x128 tile, writes fp32 distances ----------------
// grid: (TS/128, NQ/128), 256 threads = 4 waves; wave w: m_off=(w>>1)*64, n_off=(w&1)*64;
// wave tile 64x64 = 2x2 of 32x32 frags. Single 32KB buffer, 2-barrier K-loop (m97 skeleton);
// 3 blocks/CU co-resident hide the vmcnt drain (m114 overlap). No selection state at all.
// Frag map (verified 32x32x16): col=lane&31, row=(r&3)+8*(r>>2)+4*(lane>>5).
__launch_bounds__(256, 3)
__global__ void gemm_dist(const u16* __restrict__ Qh, const u16* __restrict__ Ql,
                          const u16* __restrict__ Th, const u16* __restrict__ Tl,
                          const float* __restrict__ q2, const float* __restrict__ t2,
                          float* __restrict__ D, int t0g, int tslice) {
    __shared__ __align__(16) u16 tile[4][4096];   // Ah,Al,Bh,Bl : [128][32] each (32 KB)
    __shared__ float sQ2L[128];
    __shared__ float sT2L[128];

    const int tid = threadIdx.x;
    const int lane = tid & 63;
    const int wid = tid >> 6;             // 0..3
    const int q0g = blockIdx.y * 128;
    const int tb  = t0g + blockIdx.x * 128;     // global train row base
    const int m_off = (wid >> 1) * 64;
    const int n_off = (wid & 1) * 64;
    const int swz = ((lane >> 1) & 3) << 3;     // read-side chunk swizzle (elems)
    const int l4r = lane >> 2;                  // staging row within 16-row group
    const int l4c = (((lane & 3) ^ ((lane >> 3) & 3)) * 8);  // swizzled source chunk

    if (tid < 128) { sQ2L[tid] = q2[q0g + tid]; sT2L[tid] = t2[tb + tid]; }

    float16 acc[2][2];
    acc[0][0] = (float16)(0.0f); acc[0][1] = (float16)(0.0f);
    acc[1][0] = (float16)(0.0f); acc[1][1] = (float16)(0.0f);

    #pragma unroll 1
    for (int k0 = 0; k0 < DIM; k0 += MBK) {
        __syncthreads();   // prev compute done (first iter: sQ2L/sT2L staged)
        #pragma unroll
        for (int u = 0; u < 4; ++u) {
            const u16* P = (u == 0) ? Qh : (u == 1) ? Ql : (u == 2) ? Th : Tl;
            const int rb = (u < 2) ? q0g : tb;
            #pragma unroll
            for (int j = 0; j < 2; ++j) {
                const int rg = j * 64 + wid * 16;      // wave-uniform 16-row group
                gld16(P + (size_t)(rb + rg + l4r) * DIM + k0 + l4c,
                      (u16*)tile[u] + rg * 32);
            }
        }
        __syncthreads();   // tiles ready

        #pragma unroll
        for (int s = 0; s < 2; ++s) {
            const int kb = (s * 16 + (lane >> 5) * 8) ^ swz;
            short8 ah[2], al[2], bh[2], bl[2];
            #pragma unroll
            for (int mi = 0; mi < 2; ++mi) {
                int row = m_off + mi * 32 + (lane & 31);
                ah[mi] = *(const short8*)(const void*)&tile[0][row * 32 + kb];
                al[mi] = *(const short8*)(const void*)&tile[1][row * 32 + kb];
            }
            #pragma unroll
            for (int nj = 0; nj < 2; ++nj) {
                int row = n_off + nj * 32 + (lane & 31);
                bh[nj] = *(const short8*)(const void*)&tile[2][row * 32 + kb];
                bl[nj] = *(const short8*)(const void*)&tile[3][row * 32 + kb];
            }
            #pragma unroll
            for (int mi = 0; mi < 2; ++mi)
                #pragma unroll
                for (int nj = 0; nj < 2; ++nj) {
                    acc[mi][nj] = __builtin_amdgcn_mfma_f32_32x32x16_bf16(ah[mi], bh[nj], acc[mi][nj], 0, 0, 0);
                    acc[mi][nj] = __builtin_amdgcn_mfma_f32_32x32x16_bf16(ah[mi], bl[nj], acc[mi][nj], 0, 0, 0);
                    acc[mi][nj] = __builtin_amdgcn_mfma_f32_32x32x16_bf16(al[mi], bh[nj], acc[mi][nj], 0, 0, 0);
                }
        }
    }

    // epilogue: d = max(q2 - 2*acc + t2, 0); write D[q][col] (row-major within slice).
    // Per store instr: lanes 0-31 cover 32 consecutive cols (128B seg), lanes 32-63 row+4.
    #pragma unroll
    for (int mi = 0; mi < 2; ++mi)
        #pragma unroll
        for (int nj = 0; nj < 2; ++nj) {
            const int tcol_l = n_off + nj * 32 + (lane & 31);
            const float t2v = sT2L[tcol_l];
            const size_t colg = (size_t)blockIdx.x * 128 + tcol_l;
            #pragma unroll
            for (int r = 0; r < 16; ++r) {
                const int qrow_l = m_off + mi * 32 + (r & 3) + 8 * (r >> 2) + 4 * (lane >> 5);
                float d = fmaxf(sQ2L[qrow_l] - 2.0f * acc[mi][nj][r] + t2v, 0.0f);
                D[(size_t)(q0g + qrow_l) * tslice + colg] = d;
            }
        }
}

// ---------------- knn_select: read D slice, seed-filtered top-K per (q, 2048-slice) -------
// grid: (TS/2048, NQ/QSEL=64), 256 threads. Block: 32q x 2048t. Proven filter/insert
// machinery, no MFMA attached. D is L3-resident (slice <= 256 MB) -> read is cheap.
__launch_bounds__(256, 4)
__global__ void knn_select(const float* __restrict__ D, const u32* __restrict__ seed,
                           u64* __restrict__ cand, int t0g, int tslice) {
    __shared__ u32 topkD[QSEL][KNN + 1];
    __shared__ u16 topkI[QSEL][KNN + 1];
    __shared__ u64 sbuf[QSEL][SCAP];
    __shared__ u64 kth64[QSEL];
    __shared__ u32 cnt[QSEL];
    __shared__ int againF;

    const int tid = threadIdx.x;
    const int q0 = blockIdx.y * QSEL;
    const int tb0 = blockIdx.x * 2048;            // within slice buffer
    const int gs = (t0g >> 11) + blockIdx.x;      // global 2048-slice index
    const int qq = tid >> 3;                      // 0..31 (owned q row for loads)
    const int sub = tid & 7;

    for (int i = tid; i < QSEL * (KNN + 1); i += 256) {
        ((u32*)topkD)[i] = 0xFFFFFFFFu;
        ((u16*)topkI)[i] = 0xFFFFu;
    }
    u64 seedkey = ~0ULL;
    if (tid < QSEL) {
        seedkey = ((u64)seed[q0 + tid] + 1) << 16;
        kth64[tid] = seedkey;
        cnt[tid] = 0u;
    }
    if (tid == 0) againF = 0;
    __syncthreads();

    #pragma unroll 1
    for (int c = 0; c < 2048 / 128; ++c) {
        // load 16 contiguous floats per thread (4x float4), 8 threads cover 128 t of one q row
        float v[16];
        const float4* p = (const float4*)(D + (size_t)(q0 + qq) * tslice + tb0 + c * 128 + sub * 16);
        #pragma unroll
        for (int j = 0; j < 4; ++j) {
            float4 f = p[j];
            v[4 * j + 0] = f.x; v[4 * j + 1] = f.y; v[4 * j + 2] = f.z; v[4 * j + 3] = f.w;
        }
        const int tg0 = gs * 2048 + c * 128 + sub * 16;   // global train idx of v[0]

        u32 mask = 0;
        for (;;) {
            #pragma unroll
            for (int j = 0; j < 16; ++j) {
                if ((mask >> j) & 1) continue;
                u64 key = ((u64)__float_as_uint(v[j]) << 16) | (u64)(u32)(tg0 + j);
                if (key < kth64[qq]) {
                    u32 pos = atomicAdd(&cnt[qq], 1u);
                    if (pos < SCAP) { sbuf[qq][pos] = key; mask |= (1u << j); }
                }
            }
            __syncthreads();  // sbuf/cnt complete
            if (tid < QSEL) {
                u32 n = cnt[tid];
                u32 m = n < SCAP ? n : SCAP;
                for (u32 e = 0; e < m; ++e) {
                    u64 key = sbuf[tid][e];
                    u64 last = ((u64)topkD[tid][KNN - 1] << 16) | topkI[tid][KNN - 1];
                    if (key < last) {
                        int p2 = KNN - 1;
                        while (p2 > 0) {
                            u64 prev = ((u64)topkD[tid][p2 - 1] << 16) | topkI[tid][p2 - 1];
                            if (prev > key) {
                                topkD[tid][p2] = topkD[tid][p2 - 1];
                                topkI[tid][p2] = topkI[tid][p2 - 1];
                                --p2;
                            } else break;
                        }
                        topkD[tid][p2] = (u32)(key >> 16);
                        topkI[tid][p2] = (u16)(key & 0xFFFF);
                    }
                }
                // clamp to seed: a non-full list's ~0 sentinel must NOT widen the filter
                u64 last = ((u64)topkD[tid][KNN - 1] << 16) | topkI[tid][KNN - 1];
                kth64[tid] = last < seedkey ? last : seedkey;
                if (n > SCAP) againF = 1;
                cnt[tid] = 0u;
            }
            __syncthreads();  // insert done, againF final, kth updated
            int go = againF;
            __syncthreads();  // all reads of againF done
            if (tid == 0) againF = 0;
            if (!go) break;   // uniform
            __syncthreads();  // reset visible before next pass's insert
        }
    }

    __syncthreads();
    for (int i = tid; i < QSEL * KNN; i += 256) {
        int q = i >> 5, k = i & 31;
        u64 key = ((u64)topkD[q][k] << 16) | topkI[q][k];
        cand[((size_t)(q0 + q) * NS + gs) * KNN + k] = key;
    }
}

// ---------------- tile staging for fused fallback (4 gld16/wave at 512 threads) -----------
__device__ __forceinline__ void stage_tile(const u16* __restrict__ Qh, const u16* __restrict__ Ql,
                                           const u16* __restrict__ Th, const u16* __restrict__ Tl,
                                           u16* base, int q0, int tb, int k0, int wid, int lane) {
    const int l4r = lane >> 2;
    const int l4c = (((lane & 3) ^ ((lane >> 3) & 3)) * 8);
    #pragma unroll
    for (int u = 0; u < 4; ++u) {
        const u16* P = (u == 0) ? Qh : (u == 1) ? Ql : (u == 2) ? Th : Tl;
        const int r0 = (u < 2) ? q0 : tb;
        const u16* g = P + (size_t)(r0 + wid * 16 + l4r) * DIM + k0 + l4c;
        gld16(g, base + u * 4096 + wid * 512);
    }
}

// ---------------- fused MFMA fallback (R4, proven; used only if ws too small for D) -------
__launch_bounds__(512, 1)
__global__ void knn_mfma(const u16* __restrict__ Qh, const u16* __restrict__ Ql,
                         const u16* __restrict__ Th, const u16* __restrict__ Tl,
                         const float* __restrict__ q2, const float* __restrict__ t2,
                         const u32* __restrict__ seed, u64* __restrict__ cand) {
    __shared__ __align__(16) u16 tiles[3][16384];   // 3 x 32 KB
    __shared__ u32 topkD[MQT][KNN + 1];
    __shared__ u16 topkI[MQT][KNN + 1];
    __shared__ u64 sbuf[MQT][SCAP];
    __shared__ u64 kth64[MQT];
    __shared__ u32 cnt[MQT];
    __shared__ float sQ2[MQT];
    __shared__ float sT2[MTT];
    __shared__ int againF;

    const int tid = threadIdx.x;
    const int lane = tid & 63;
    const int wid = tid >> 6;
    const int q0 = blockIdx.y * MQT;
    const int s0 = blockIdx.x * MSLICE;
    const int m_off = (wid >> 2) * 64;
    const int n_off = (wid & 3) * 32;
    const int swz = ((lane >> 1) & 3) << 3;

    for (int i = tid; i < MQT * (KNN + 1); i += 512) {
        ((u32*)topkD)[i] = 0xFFFFFFFFu;
        ((u16*)topkI)[i] = 0xFFFFu;
    }
    u64 seedkey = ~0ULL;
    if (tid < MQT) {
        seedkey = ((u64)seed[q0 + tid] + 1) << 16;
        kth64[tid] = seedkey;
        cnt[tid] = 0u;
        sQ2[tid] = q2[q0 + tid];
    }
    if (tid == 0) againF = 0;

    stage_tile(Qh, Ql, Th, Tl, tiles[0], q0, s0, 0, wid, lane);
    stage_tile(Qh, Ql, Th, Tl, tiles[1], q0, s0, MBK, wid, lane);
    __syncthreads();

    int cb = 0;
    #pragma unroll 1
    for (int chunk = 0; chunk < MSLICE / MTT; ++chunk) {
        const int tb = s0 + chunk * MTT;
        float16 acc[2];
        acc[0] = (float16)(0.0f);
        acc[1] = (float16)(0.0f);

        #pragma unroll 1
        for (int t = 0; t < DIM / MBK; ++t) {
            const int Tn = chunk * 16 + t + 2;
            const bool pf = (Tn < NTILES);
            if (pf) {
                int bn = cb + 2; if (bn >= 3) bn -= 3;
                stage_tile(Qh, Ql, Th, Tl, tiles[bn], q0,
                           s0 + (Tn >> 4) * MTT, (Tn & 15) * MBK, wid, lane);
            }
            const u16* sAh = tiles[cb];
            const u16* sAl = sAh + 4096;
            const u16* sBh = sAh + 8192;
            const u16* sBl = sAh + 12288;
            #pragma unroll
            for (int s = 0; s < 2; ++s) {
                const int kb = (s * 16 + (lane >> 5) * 8) ^ swz;
                short8 ah[2], al[2];
                #pragma unroll
                for (int mi = 0; mi < 2; ++mi) {
                    int row = m_off + mi * 32 + (lane & 31);
                    ah[mi] = *(const short8*)(const void*)&sAh[row * MBK + kb];
                    al[mi] = *(const short8*)(const void*)&sAl[row * MBK + kb];
                }
                int brow = n_off + (lane & 31);
                short8 bh = *(const short8*)(const void*)&sBh[brow * MBK + kb];
                short8 bl = *(const short8*)(const void*)&sBl[brow * MBK + kb];
                #pragma unroll
                for (int mi = 0; mi < 2; ++mi) {
                    acc[mi] = __builtin_amdgcn_mfma_f32_32x32x16_bf16(ah[mi], bh, acc[mi], 0, 0, 0);
                    acc[mi] = __builtin_amdgcn_mfma_f32_32x32x16_bf16(ah[mi], bl, acc[mi], 0, 0, 0);
                    acc[mi] = __builtin_amdgcn_mfma_f32_32x32x16_bf16(al[mi], bh, acc[mi], 0, 0, 0);
                }
            }
            if (pf) asm volatile("s_waitcnt vmcnt(4)" ::: "memory");
            else    asm volatile("s_waitcnt vmcnt(0)" ::: "memory");
            __builtin_amdgcn_s_barrier();
            __builtin_amdgcn_sched_barrier(0);
            ++cb; if (cb >= 3) cb = 0;
        }

        if (tid < MTT) sT2[tid] = t2[tb + tid];
        __syncthreads();
        const float t2r = sT2[n_off + (lane & 31)];
        const int tcol = n_off + (lane & 31);

        u32 mask = 0;
        for (;;) {
            #pragma unroll
            for (int mi = 0; mi < 2; ++mi) {
                #pragma unroll
                for (int r = 0; r < 16; ++r) {
                    const int bit = mi * 16 + r;
                    if ((mask >> bit) & 1) continue;
                    const int qrow = m_off + mi * 32 + (r & 3) + 8 * (r >> 2) + 4 * (lane >> 5);
                    float d = fmaxf(sQ2[qrow] - 2.0f * acc[mi][r] + t2r, 0.0f);
                    u64 key = ((u64)__float_as_uint(d) << 16) | (u64)(u32)(tb + tcol);
                    if (key < kth64[qrow]) {
                        u32 pos = atomicAdd(&cnt[qrow], 1u);
                        if (pos < SCAP) { sbuf[qrow][pos] = key; mask |= (1u << bit); }
                    }
                }
            }
            __syncthreads();
            if (tid < MQT) {
                u32 n = cnt[tid];
                u32 m = n < SCAP ? n : SCAP;
                for (u32 e = 0; e < m; ++e) {
                    u64 key = sbuf[tid][e];
                    u64 last = ((u64)topkD[tid][KNN - 1] << 16) | topkI[tid][KNN - 1];
                    if (key < last) {
                        int p = KNN - 1;
                        while (p > 0) {
                            u64 prev = ((u64)topkD[tid][p - 1] << 16) | topkI[tid][p - 1];
                            if (prev > key) {
                                topkD[tid][p] = topkD[tid][p - 1];
                                topkI[tid][p] = topkI[tid][p - 1];
                                --p;
                            } else break;
                        }
                        topkD[tid][p] = (u32)(key >> 16);
                        topkI[tid][p] = (u16)(key & 0xFFFF);
                    }
                }
                u64 last = ((u64)topkD[tid][KNN - 1] << 16) | topkI[tid][KNN - 1];
                kth64[tid] = last < seedkey ? last : seedkey;
                if (n > SCAP) againF = 1;
                cnt[tid] = 0u;
            }
            __syncthreads();
            int go = againF;
            __syncthreads();
            if (tid == 0) againF = 0;
            if (!go) break;
            __syncthreads();
        }
    }

    __syncthreads();
    for (int i = tid; i < MQT * KNN; i += 512) {
        int q = i >> 5, k = i & 31;
        u64 key = ((u64)topkD[q][k] << 16) | topkI[q][k];
        cand[((size_t)(q0 + q) * NS + blockIdx.x) * KNN + k] = key;
    }
}

// ---------------- fallback: fp32 distance + per-slice top-K (proven) ----------------
__launch_bounds__(256, 4)
__global__ void knn_part(const float* __restrict__ Xq, const float* __restrict__ Xt,
                         const float* __restrict__ q2, const float* __restrict__ t2,
                         u64* __restrict__ cand) {
    __shared__ float sQ[KK][QT];
    __shared__ float sT[KK][TT];
    __shared__ u64 topk[QT][KNN];
    __shared__ u64 buf[QT][FCAP];
    __shared__ u64 kth64[QT];
    __shared__ u32 cnt[QT];
    __shared__ int againF;

    const int tid = threadIdx.x;
    const int q0 = blockIdx.x * QT;
    const int t0 = blockIdx.y * SLICE;
    const int tq4 = (tid >> 5) * 4;
    const int tt4 = (tid & 31) * 4;
    const int pg = tid & 63;
    const int kg = tid >> 6;
    const int qp = tid & 31;
    const int kq = tid >> 5;

    for (int i = tid; i < QT * KNN; i += 256) ((u64*)topk)[i] = ~0ULL;
    if (tid < QT) { kth64[tid] = ~0ULL; cnt[tid] = 0u; }
    if (tid == 0) againF = 0;

    float qq[4];
    #pragma unroll
    for (int i = 0; i < 4; ++i) qq[i] = q2[q0 + tq4 + i];

    #pragma unroll 1
    for (int chunk = 0; chunk < SLICE / TT; ++chunk) {
        const int tbase = t0 + chunk * TT;
        float acc[4][8];
        #pragma unroll
        for (int i = 0; i < 4; ++i)
            #pragma unroll
            for (int j = 0; j < 8; ++j) acc[i][j] = 0.f;

        #pragma unroll 1
        for (int k0 = 0; k0 < DIM; k0 += KK) {
            __syncthreads();
            {
                const float* Tp = Xt + (size_t)(tbase + pg * 4) * DIM + k0 + kg * 4;
                float4 r0 = *(const float4*)(Tp);
                float4 r1 = *(const float4*)(Tp + DIM);
                float4 r2 = *(const float4*)(Tp + 2 * DIM);
                float4 r3 = *(const float4*)(Tp + 3 * DIM);
                *(float4*)&sT[kg * 4 + 0][pg * 4] = make_float4(r0.x, r1.x, r2.x, r3.x);
                *(float4*)&sT[kg * 4 + 1][pg * 4] = make_float4(r0.y, r1.y, r2.y, r3.y);
                *(float4*)&sT[kg * 4 + 2][pg * 4] = make_float4(r0.z, r1.z, r2.z, r3.z);
                *(float4*)&sT[kg * 4 + 3][pg * 4] = make_float4(r0.w, r1.w, r2.w, r3.w);
            }
            {
                float2 v = *(const float2*)(Xq + (size_t)(q0 + qp) * DIM + k0 + kq * 2);
                sQ[kq * 2 + 0][qp] = v.x;
                sQ[kq * 2 + 1][qp] = v.y;
            }
            __syncthreads();
            #pragma unroll
            for (int k = 0; k < KK; ++k) {
                float4 qv = *(const float4*)&sQ[k][tq4];
                float4 ta = *(const float4*)&sT[k][tt4];
                float4 tb = *(const float4*)&sT[k][128 + tt4];
                float qa[4] = {qv.x, qv.y, qv.z, qv.w};
                float tv[8] = {ta.x, ta.y, ta.z, ta.w, tb.x, tb.y, tb.z, tb.w};
                #pragma unroll
                for (int i = 0; i < 4; ++i)
                    #pragma unroll
                    for (int j = 0; j < 8; ++j)
                        acc[i][j] = fmaf(qa[i], tv[j], acc[i][j]);
            }
        }

        float t2v[8];
        #pragma unroll
        for (int j = 0; j < 4; ++j) {
            t2v[j]     = t2[tbase + tt4 + j];
            t2v[4 + j] = t2[tbase + 128 + tt4 + j];
        }
        #pragma unroll
        for (int i = 0; i < 4; ++i)
            #pragma unroll
            for (int j = 0; j < 8; ++j)
                acc[i][j] = fmaxf((qq[i] - 2.f * acc[i][j]) + t2v[j], 0.f);

        unsigned mask = 0;
        for (;;) {
            u64 kv[4];
            #pragma unroll
            for (int i = 0; i < 4; ++i) kv[i] = kth64[tq4 + i];
            #pragma unroll
            for (int i = 0; i < 4; ++i) {
                #pragma unroll
                for (int j = 0; j < 8; ++j) {
                    unsigned b = 1u << (i * 8 + j);
                    if (mask & b) continue;
                    int tloc = (j < 4) ? (tt4 + j) : (128 + tt4 + (j - 4));
                    u64 key = ((u64)__float_as_uint(acc[i][j]) << 16) |
                              (u64)(unsigned)(tbase + tloc);
                    if (key < kv[i]) {
                        unsigned pos = atomicAdd(&cnt[tq4 + i], 1u);
                        if (pos < FCAP) { buf[tq4 + i][pos] = key; mask |= b; }
                    }
                }
            }
            __syncthreads();
            if (tid < QT) {
                unsigned n = cnt[tid];
                unsigned m = n < FCAP ? n : FCAP;
                for (unsigned e = 0; e < m; ++e) {
                    u64 key = buf[tid][e];
                    if (key < topk[tid][KNN - 1]) {
                        int p = KNN - 1;
                        while (p > 0 && topk[tid][p - 1] > key) {
                            topk[tid][p] = topk[tid][p - 1];
                            --p;
                        }
                        topk[tid][p] = key;
                    }
                }
                kth64[tid] = topk[tid][KNN - 1];
                if (n > FCAP) againF = 1;
                cnt[tid] = 0u;
            }
            __syncthreads();
            int go = againF;
            __syncthreads();
            if (tid == 0) againF = 0;
            if (!go) break;
            __syncthreads();
        }
    }

    __syncthreads();
    for (int i = tid; i < QT * KNN; i += 256) {
        int q = i >> 5, k = i & 31;
        cand[((size_t)(q0 + q) * NS + blockIdx.y) * KNN + k] = topk[q][k];
    }
}

// ---------------- merge + vote ----------------
__global__ void knn_merge(const u64* __restrict__ cand,
                          const int* __restrict__ y_train, int* __restrict__ out) {
    __shared__ u64 keys[NS * KNN];
    __shared__ u64 top[KNN];
    __shared__ int counts[NC];
    int q = blockIdx.x;
    for (int i = threadIdx.x; i < NS * KNN; i += 64)
        keys[i] = cand[(size_t)q * NS * KNN + i];
    for (int i = threadIdx.x; i < NC; i += 64) counts[i] = 0;
    if (threadIdx.x < KNN) top[threadIdx.x] = ~0ULL;
    __syncthreads();

    if (threadIdx.x == 0) {
        for (int s = 0; s < NS; ++s) {
            for (int j = 0; j < KNN; ++j) {
                u64 key = keys[s * KNN + j];
                if (key >= top[KNN - 1]) break;
                int p = KNN - 1;
                while (p > 0 && top[p - 1] > key) { top[p] = top[p - 1]; --p; }
                top[p] = key;
            }
        }
        for (int k = 0; k < KNN; ++k) {
            int idx = (int)(top[k] & 0xFFFF);
            counts[y_train[idx]]++;
        }
        int bestc = counts[0], bestl = 0;
        for (int c = 1; c < NC; ++c)
            if (counts[c] > bestc) { bestc = counts[c]; bestl = c; }
        out[q] = bestl;
    }
}

extern "C" void kernel_launch(void* const* d_in, const int* in_sizes, int n_in,
                              void* d_out, int out_size, void* d_ws, size_t ws_size,
                              hipStream_t stream) {
    const float* Xq = (const float*)d_in[0];   // [2048, 512]
    const float* Xt = (const float*)d_in[1];   // [65536, 512]
    const int*   y  = (const int*)d_in[2];     // [65536]
    int* out = (int*)d_out;                    // [2048] int32

    float* t2 = (float*)d_ws;                                   // 256 KB
    float* q2 = t2 + NT;                                        // 8 KB
    u64* cand = (u64*)(q2 + NQ);                                // 16.8 MB
    u32* seed = (u32*)(cand + (size_t)NQ * NS * KNN);           // 8 KB
    u16* Qh = (u16*)(seed + NQ);                                // 2 MB
    u16* Ql = Qh + (size_t)NQ * DIM;                            // 2 MB
    u16* Th = Ql + (size_t)NQ * DIM;                            // 64 MB
    u16* Tl = Th + (size_t)NT * DIM;                            // 64 MB
    float* Dbuf = (float*)(Tl + (size_t)NT * DIM);              // distance slice buffer
    const size_t need = (size_t)(NT + NQ) * 4
                      + (size_t)NQ * NS * KNN * 8
                      + (size_t)NQ * 4
                      + 2 * ((size_t)NQ * DIM + (size_t)NT * DIM) * 2;  // ~148.3 MB
    const bool use_mfma = ws_size >= need;

    // D-slice tier: prefer the largest slice that fits the remaining workspace
    size_t extra = ws_size > need ? ws_size - need : 0;
    int TS = 0;
    if      (extra >= (size_t)NQ * 65536 * 4) TS = 65536;   // +512 MB, 1 pair
    else if (extra >= (size_t)NQ * 16384 * 4) TS = 16384;   // +128 MB, 4 pairs
    else if (extra >= (size_t)NQ * 8192 * 4)  TS = 8192;    // +64 MB, 8 pairs

    norm_kernel<<<NT / 4, 256, 0, stream>>>(Xt, t2, NT);
    norm_kernel<<<NQ / 4, 256, 0, stream>>>(Xq, q2, NQ);
    if (use_mfma) {
        hipMemsetAsync(seed, 0xFF, NQ * sizeof(u32), stream);
        split_kernel<<<(NQ * DIM / 4 + 255) / 256, 256, 0, stream>>>(Xq, Qh, Ql, NQ * DIM / 4);
        split_kernel<<<(NT * DIM / 4 + 255) / 256, 256, 0, stream>>>(Xt, Th, Tl, NT * DIM / 4);
        knn_prepass<<<dim3(NQ / PQT, NTPRE / PSLICE), 256, 0, stream>>>(Xq, Xt, q2, t2, seed);
        if (TS) {
            for (int t0g = 0; t0g < NT; t0g += TS) {
                gemm_dist<<<dim3(TS / 128, NQ / 128), 256, 0, stream>>>(
                    Qh, Ql, Th, Tl, q2, t2, Dbuf, t0g, TS);
                knn_select<<<dim3(TS / 2048, NQ / QSEL), 256, 0, stream>>>(
                    Dbuf, seed, cand, t0g, TS);
            }
        } else {
            knn_mfma<<<dim3(NT / MSLICE, NQ / MQT), 512, 0, stream>>>(Qh, Ql, Th, Tl, q2, t2, seed, cand);
        }
    } else {
        knn_part<<<dim3(NQ / QT, NS), 256, 0, stream>>>(Xq, Xt, q2, t2, cand);
    }
    knn_merge<<<NQ, 64, 0, stream>>>(cand, y, out);
}

// Round 6
// 2221.708 us; speedup vs baseline: 1.6352x; 1.6352x over previous
//
#include <hip/hip_runtime.h>
#include <hip/hip_bf16.h>
#include <stdint.h>

typedef unsigned long long u64;
typedef unsigned int u32;
typedef unsigned short u16;
typedef __attribute__((ext_vector_type(8))) short short8;
typedef __attribute__((ext_vector_type(16))) float float16;

#define NQ 2048
#define NT 65536
#define DIM 512
#define KNN 32
#define NC 100
#define NS 32               // slices (fallback paths), cand[q][slice][k]

// ---- fallback (R2) params ----
#define QT 32
#define SLICE (NT / NS)     // 2048
#define TT 256
#define KK 16
#define FCAP 32

// ---- prepass params (fp32, trains 0..2047 subsample) ----
#define PQT 32
#define PTT 256
#define PSLICE 512
#define NTPRE 2048

// ---- fused-mfma fallback params (R4, proven) ----
#define MQT 128
#define MTT 128
#define MBK 32
#define MSLICE 2048
#define SCAP 16
#define NTILES 256

// ---- R6 filter-path params ----
#define GCAP 4096           // per-query candidate capacity; exact-2048 seed admits ~1024±180 (17 sigma)

// ---------------- row-norm kernel ----------------
__global__ void norm_kernel(const float* __restrict__ X, float* __restrict__ out, int nrows) {
    int row = blockIdx.x * 4 + (threadIdx.x >> 6);
    int lane = threadIdx.x & 63;
    if (row >= nrows) return;
    const float4* p = (const float4*)(X + (size_t)row * DIM);
    float4 a = p[lane];
    float4 b = p[lane + 64];
    float s = a.x*a.x + a.y*a.y + a.z*a.z + a.w*a.w
            + b.x*b.x + b.y*b.y + b.z*b.z + b.w*b.w;
    #pragma unroll
    for (int off = 32; off > 0; off >>= 1) s += __shfl_down(s, off, 64);
    if (lane == 0) out[row] = s;
}

// ---------------- bf16 hi/lo split ----------------
__global__ void split_kernel(const float* __restrict__ X, u16* __restrict__ H,
                             u16* __restrict__ L, int n4) {
    int i = blockIdx.x * 256 + threadIdx.x;
    if (i >= n4) return;
    float4 v = ((const float4*)X)[i];
    float f[4] = {v.x, v.y, v.z, v.w};
    u16 hh[4], ll[4];
    #pragma unroll
    for (int j = 0; j < 4; ++j) {
        union { __hip_bfloat16 b; u16 u; } cv;
        cv.b = __float2bfloat16(f[j]);
        hh[j] = cv.u;
        float hf = __bfloat162float(cv.b);
        cv.b = __float2bfloat16(f[j] - hf);
        ll[j] = cv.u;
    }
    ((ushort4*)H)[i] = make_ushort4(hh[0], hh[1], hh[2], hh[3]);
    ((ushort4*)L)[i] = make_ushort4(ll[0], ll[1], ll[2], ll[3]);
}

// ---------------- knn_pre: fp32 distances for trains 0..2047, written to Dpre --------------
// grid: (NQ/PQT=64, NTPRE/PSLICE=4), 256 thr. Pure compute+store; no selection protocol.
__launch_bounds__(256, 2)
__global__ void knn_pre(const float* __restrict__ Xq, const float* __restrict__ Xt,
                        const float* __restrict__ q2, const float* __restrict__ t2,
                        float* __restrict__ Dpre) {
    __shared__ float sQ[KK][PQT];
    __shared__ float sT[KK][PTT];

    const int tid = threadIdx.x;
    const int q0 = blockIdx.x * PQT;
    const int t0p = blockIdx.y * PSLICE;
    const int tq4 = (tid >> 5) * 4;
    const int tt4 = (tid & 31) * 4;
    const int pg = tid & 63;
    const int kg = tid >> 6;
    const int qp = tid & 31;
    const int kq = tid >> 5;

    float qq[4];
    #pragma unroll
    for (int i = 0; i < 4; ++i) qq[i] = q2[q0 + tq4 + i];

    #pragma unroll 1
    for (int chunk = 0; chunk < PSLICE / PTT; ++chunk) {
        const int tbase = t0p + chunk * PTT;
        float acc[4][8];
        #pragma unroll
        for (int i = 0; i < 4; ++i)
            #pragma unroll
            for (int j = 0; j < 8; ++j) acc[i][j] = 0.f;

        #pragma unroll 1
        for (int k0 = 0; k0 < DIM; k0 += KK) {
            __syncthreads();   // protects sQ/sT reuse
            {
                const float* Tp = Xt + (size_t)(tbase + pg * 4) * DIM + k0 + kg * 4;
                float4 r0 = *(const float4*)(Tp);
                float4 r1 = *(const float4*)(Tp + DIM);
                float4 r2 = *(const float4*)(Tp + 2 * DIM);
                float4 r3 = *(const float4*)(Tp + 3 * DIM);
                *(float4*)&sT[kg * 4 + 0][pg * 4] = make_float4(r0.x, r1.x, r2.x, r3.x);
                *(float4*)&sT[kg * 4 + 1][pg * 4] = make_float4(r0.y, r1.y, r2.y, r3.y);
                *(float4*)&sT[kg * 4 + 2][pg * 4] = make_float4(r0.z, r1.z, r2.z, r3.z);
                *(float4*)&sT[kg * 4 + 3][pg * 4] = make_float4(r0.w, r1.w, r2.w, r3.w);
            }
            {
                float2 v = *(const float2*)(Xq + (size_t)(q0 + qp) * DIM + k0 + kq * 2);
                sQ[kq * 2 + 0][qp] = v.x;
                sQ[kq * 2 + 1][qp] = v.y;
            }
            __syncthreads();
            #pragma unroll
            for (int k = 0; k < KK; ++k) {
                float4 qv = *(const float4*)&sQ[k][tq4];
                float4 ta = *(const float4*)&sT[k][tt4];
                float4 tb = *(const float4*)&sT[k][128 + tt4];
                float qa[4] = {qv.x, qv.y, qv.z, qv.w};
                float tv[8] = {ta.x, ta.y, ta.z, ta.w, tb.x, tb.y, tb.z, tb.w};
                #pragma unroll
                for (int i = 0; i < 4; ++i)
                    #pragma unroll
                    for (int j = 0; j < 8; ++j)
                        acc[i][j] = fmaf(qa[i], tv[j], acc[i][j]);
            }
        }

        float t2v[8];
        #pragma unroll
        for (int j = 0; j < 4; ++j) {
            t2v[j]     = t2[tbase + tt4 + j];
            t2v[4 + j] = t2[tbase + 128 + tt4 + j];
        }
        #pragma unroll
        for (int i = 0; i < 4; ++i) {
            float4 lo, hi;
            lo.x = fmaxf(qq[i] - 2.f * acc[i][0] + t2v[0], 0.f);
            lo.y = fmaxf(qq[i] - 2.f * acc[i][1] + t2v[1], 0.f);
            lo.z = fmaxf(qq[i] - 2.f * acc[i][2] + t2v[2], 0.f);
            lo.w = fmaxf(qq[i] - 2.f * acc[i][3] + t2v[3], 0.f);
            hi.x = fmaxf(qq[i] - 2.f * acc[i][4] + t2v[4], 0.f);
            hi.y = fmaxf(qq[i] - 2.f * acc[i][5] + t2v[5], 0.f);
            hi.z = fmaxf(qq[i] - 2.f * acc[i][6] + t2v[6], 0.f);
            hi.w = fmaxf(qq[i] - 2.f * acc[i][7] + t2v[7], 0.f);
            *(float4*)&Dpre[(size_t)(q0 + tq4 + i) * NTPRE + tbase + tt4] = lo;
            *(float4*)&Dpre[(size_t)(q0 + tq4 + i) * NTPRE + tbase + 128 + tt4] = hi;
        }
    }
}

// ---------------- seed_topk: exact 32nd-smallest of Dpre row -> seed[q] -------------------
// grid: NQ blocks x 64 threads (one wave per query). Per-lane sorted-32 in LDS (padded rows),
// then 32x wave-min extraction; the 32nd extracted value is the seed.
__launch_bounds__(64)
__global__ void seed_topk(const float* __restrict__ Dpre, u32* __restrict__ seed) {
    __shared__ u64 ll[64][KNN + 1];   // pad: stride 33 u64 -> 2-way banks only
    const int q = blockIdx.x;
    const int lane = threadIdx.x;
    #pragma unroll
    for (int j = 0; j <= KNN; ++j) ll[lane][j] = ~0ULL;
    const float* src = Dpre + (size_t)q * NTPRE;
    u64 kth = ~0ULL;
    for (int i = lane; i < NTPRE; i += 64) {
        u64 key = (u64)__float_as_uint(src[i]);
        if (key < kth) {
            int p = KNN - 1;
            while (p > 0 && ll[lane][p - 1] > key) { ll[lane][p] = ll[lane][p - 1]; --p; }
            ll[lane][p] = key;
            kth = ll[lane][KNN - 1];
        }
    }
    __syncthreads();
    int ptr = 0;
    u64 cur = ll[lane][0];
    u64 m = 0;
    for (int it = 0; it < KNN; ++it) {
        m = cur;
        #pragma unroll
        for (int off = 32; off > 0; off >>= 1) {
            u64 o = __shfl_xor(m, off, 64);
            m = (o < m) ? o : m;
        }
        u64 got = __ballot(cur == m);
        int w = __ffsll(got) - 1;
        if (lane == w) { ++ptr; cur = (ptr < KNN) ? ll[lane][ptr] : ~0ULL; }
    }
    if (lane == 0) seed[q] = (u32)m;   // 32nd smallest dist bits (exact over 2048 subsample)
}

// ---------------- async global->LDS 16B ----------------
__device__ __forceinline__ void gld16(const void* g, void* l) {
    __builtin_amdgcn_global_load_lds(
        (const __attribute__((address_space(1))) u32*)g,
        (__attribute__((address_space(3))) u32*)l, 16, 0, 0);
}

// ---------------- gemm_filter: m97-style 128x128 GEMM + seed-filter push epilogue ---------
// grid: (NT/128=512, NQ/128=16), 256 thr = 4 waves. No D materialization: survivors
// (d_bits <= seed+margin, ~2 per (q,128t)) are pushed straight to glist[q] via one atomic.
// Margin 256 ulps absorbs bf16-split vs fp32 boundary epsilon (est err ~130 ulps).
__launch_bounds__(256, 3)
__global__ void gemm_filter(const u16* __restrict__ Qh, const u16* __restrict__ Ql,
                            const u16* __restrict__ Th, const u16* __restrict__ Tl,
                            const float* __restrict__ q2, const float* __restrict__ t2,
                            const u32* __restrict__ seed,
                            u32* __restrict__ gcnt, u64* __restrict__ glist) {
    __shared__ __align__(16) u16 tile[4][4096];   // Ah,Al,Bh,Bl : [128][32] each (32 KB)
    __shared__ float sQ2L[128];
    __shared__ float sT2L[128];
    __shared__ u32 sSeed[128];

    const int tid = threadIdx.x;
    const int lane = tid & 63;
    const int wid = tid >> 6;             // 0..3
    const int q0g = blockIdx.y * 128;
    const int tb  = blockIdx.x * 128;     // global train row base
    const int m_off = (wid >> 1) * 64;
    const int n_off = (wid & 1) * 64;
    const int swz = ((lane >> 1) & 3) << 3;
    const int l4r = lane >> 2;
    const int l4c = (((lane & 3) ^ ((lane >> 3) & 3)) * 8);

    if (tid < 128) {
        sQ2L[tid] = q2[q0g + tid];
        sT2L[tid] = t2[tb + tid];
        sSeed[tid] = seed[q0g + tid] + 256u;   // admission threshold (+ulp margin)
    }

    float16 acc[2][2];
    acc[0][0] = (float16)(0.0f); acc[0][1] = (float16)(0.0f);
    acc[1][0] = (float16)(0.0f); acc[1][1] = (float16)(0.0f);

    #pragma unroll 1
    for (int k0 = 0; k0 < DIM; k0 += MBK) {
        __syncthreads();   // prev compute done (first iter: sQ2L/sT2L/sSeed staged)
        #pragma unroll
        for (int u = 0; u < 4; ++u) {
            const u16* P = (u == 0) ? Qh : (u == 1) ? Ql : (u == 2) ? Th : Tl;
            const int rb = (u < 2) ? q0g : tb;
            #pragma unroll
            for (int j = 0; j < 2; ++j) {
                const int rg = j * 64 + wid * 16;
                gld16(P + (size_t)(rb + rg + l4r) * DIM + k0 + l4c,
                      (u16*)tile[u] + rg * 32);
            }
        }
        __syncthreads();   // tiles ready

        #pragma unroll
        for (int s = 0; s < 2; ++s) {
            const int kb = (s * 16 + (lane >> 5) * 8) ^ swz;
            short8 ah[2], al[2], bh[2], bl[2];
            #pragma unroll
            for (int mi = 0; mi < 2; ++mi) {
                int row = m_off + mi * 32 + (lane & 31);
                ah[mi] = *(const short8*)(const void*)&tile[0][row * 32 + kb];
                al[mi] = *(const short8*)(const void*)&tile[1][row * 32 + kb];
            }
            #pragma unroll
            for (int nj = 0; nj < 2; ++nj) {
                int row = n_off + nj * 32 + (lane & 31);
                bh[nj] = *(const short8*)(const void*)&tile[2][row * 32 + kb];
                bl[nj] = *(const short8*)(const void*)&tile[3][row * 32 + kb];
            }
            #pragma unroll
            for (int mi = 0; mi < 2; ++mi)
                #pragma unroll
                for (int nj = 0; nj < 2; ++nj) {
                    acc[mi][nj] = __builtin_amdgcn_mfma_f32_32x32x16_bf16(ah[mi], bh[nj], acc[mi][nj], 0, 0, 0);
                    acc[mi][nj] = __builtin_amdgcn_mfma_f32_32x32x16_bf16(ah[mi], bl[nj], acc[mi][nj], 0, 0, 0);
                    acc[mi][nj] = __builtin_amdgcn_mfma_f32_32x32x16_bf16(al[mi], bh[nj], acc[mi][nj], 0, 0, 0);
                }
        }
    }

    // epilogue: rare filtered push (frag map: col=lane&31, row=(r&3)+8*(r>>2)+4*(lane>>5))
    #pragma unroll
    for (int mi = 0; mi < 2; ++mi)
        #pragma unroll
        for (int nj = 0; nj < 2; ++nj) {
            const int tcol_l = n_off + nj * 32 + (lane & 31);
            const float t2v = sT2L[tcol_l];
            #pragma unroll
            for (int r = 0; r < 16; ++r) {
                const int qrow_l = m_off + mi * 32 + (r & 3) + 8 * (r >> 2) + 4 * (lane >> 5);
                float d = fmaxf(sQ2L[qrow_l] - 2.0f * acc[mi][nj][r] + t2v, 0.0f);
                if (__float_as_uint(d) <= sSeed[qrow_l]) {
                    const int q = q0g + qrow_l;
                    u32 pos = atomicAdd(&gcnt[q], 1u);
                    if (pos < GCAP)
                        glist[(size_t)q * GCAP + pos] =
                            ((u64)__float_as_uint(d) << 16) | (u64)(u32)(tb + tcol_l);
                }
            }
        }
}

// ---------------- knn_topk: exact top-32 over candidate list + vote -> out ----------------
// grid: NQ blocks x 64 threads (one wave per query). n ~ 1024 (seed guarantees n >= 32).
__launch_bounds__(64)
__global__ void knn_topk(const u64* __restrict__ glist, const u32* __restrict__ gcnt,
                         const int* __restrict__ y_train, int* __restrict__ out) {
    __shared__ u64 ll[64][KNN + 1];
    __shared__ u64 fin[KNN];
    __shared__ int counts[NC];
    const int q = blockIdx.x;
    const int lane = threadIdx.x;
    #pragma unroll
    for (int j = 0; j <= KNN; ++j) ll[lane][j] = ~0ULL;
    for (int i = lane; i < NC; i += 64) counts[i] = 0;
    u32 n = gcnt[q]; if (n > GCAP) n = GCAP;
    const u64* src = glist + (size_t)q * GCAP;
    u64 kth = ~0ULL;
    for (u32 i = lane; i < n; i += 64) {
        u64 key = src[i];
        if (key < kth) {
            int p = KNN - 1;
            while (p > 0 && ll[lane][p - 1] > key) { ll[lane][p] = ll[lane][p - 1]; --p; }
            ll[lane][p] = key;
            kth = ll[lane][KNN - 1];
        }
    }
    __syncthreads();
    int ptr = 0;
    u64 cur = ll[lane][0];
    for (int it = 0; it < KNN; ++it) {
        u64 m = cur;
        #pragma unroll
        for (int off = 32; off > 0; off >>= 1) {
            u64 o = __shfl_xor(m, off, 64);
            m = (o < m) ? o : m;
        }
        u64 got = __ballot(cur == m);
        int w = __ffsll(got) - 1;
        if (lane == 0) fin[it] = m;
        if (lane == w) { ++ptr; cur = (ptr < KNN) ? ll[lane][ptr] : ~0ULL; }
    }
    __syncthreads();
    if (lane < KNN) {
        int idx = (int)(fin[lane] & 0xFFFF);
        atomicAdd(&counts[y_train[idx]], 1);
    }
    __syncthreads();
    if (lane == 0) {
        int bestc = counts[0], bestl = 0;
        for (int c = 1; c < NC; ++c)
            if (counts[c] > bestc) { bestc = counts[c]; bestl = c; }
        out[q] = bestl;
    }
}

// ================= fallback machinery (R4 fused path + fp32 path), proven =================

// old prepass with min-of-4x512 seed (fallback fused path only)
__launch_bounds__(256, 2)
__global__ void knn_prepass(const float* __restrict__ Xq, const float* __restrict__ Xt,
                            const float* __restrict__ q2, const float* __restrict__ t2,
                            u32* __restrict__ seed) {
    __shared__ float sQ[KK][PQT];
    __shared__ float sT[KK][PTT];
    __shared__ float sD[PQT][PTT + 1];
    __shared__ u32 topk[PQT][KNN + 1];

    const int tid = threadIdx.x;
    const int q0 = blockIdx.x * PQT;
    const int t0p = blockIdx.y * PSLICE;
    const int tq4 = (tid >> 5) * 4;
    const int tt4 = (tid & 31) * 4;
    const int pg = tid & 63;
    const int kg = tid >> 6;
    const int qp = tid & 31;
    const int kq = tid >> 5;

    for (int i = tid; i < PQT * (KNN + 1); i += 256) ((u32*)topk)[i] = 0xFFFFFFFFu;
    u32 kth = 0xFFFFFFFFu;

    float qq[4];
    #pragma unroll
    for (int i = 0; i < 4; ++i) qq[i] = q2[q0 + tq4 + i];

    #pragma unroll 1
    for (int chunk = 0; chunk < PSLICE / PTT; ++chunk) {
        const int tbase = t0p + chunk * PTT;
        float acc[4][8];
        #pragma unroll
        for (int i = 0; i < 4; ++i)
            #pragma unroll
            for (int j = 0; j < 8; ++j) acc[i][j] = 0.f;

        #pragma unroll 1
        for (int k0 = 0; k0 < DIM; k0 += KK) {
            __syncthreads();
            {
                const float* Tp = Xt + (size_t)(tbase + pg * 4) * DIM + k0 + kg * 4;
                float4 r0 = *(const float4*)(Tp);
                float4 r1 = *(const float4*)(Tp + DIM);
                float4 r2 = *(const float4*)(Tp + 2 * DIM);
                float4 r3 = *(const float4*)(Tp + 3 * DIM);
                *(float4*)&sT[kg * 4 + 0][pg * 4] = make_float4(r0.x, r1.x, r2.x, r3.x);
                *(float4*)&sT[kg * 4 + 1][pg * 4] = make_float4(r0.y, r1.y, r2.y, r3.y);
                *(float4*)&sT[kg * 4 + 2][pg * 4] = make_float4(r0.z, r1.z, r2.z, r3.z);
                *(float4*)&sT[kg * 4 + 3][pg * 4] = make_float4(r0.w, r1.w, r2.w, r3.w);
            }
            {
                float2 v = *(const float2*)(Xq + (size_t)(q0 + qp) * DIM + k0 + kq * 2);
                sQ[kq * 2 + 0][qp] = v.x;
                sQ[kq * 2 + 1][qp] = v.y;
            }
            __syncthreads();
            #pragma unroll
            for (int k = 0; k < KK; ++k) {
                float4 qv = *(const float4*)&sQ[k][tq4];
                float4 ta = *(const float4*)&sT[k][tt4];
                float4 tb = *(const float4*)&sT[k][128 + tt4];
                float qa[4] = {qv.x, qv.y, qv.z, qv.w};
                float tv[8] = {ta.x, ta.y, ta.z, ta.w, tb.x, tb.y, tb.z, tb.w};
                #pragma unroll
                for (int i = 0; i < 4; ++i)
                    #pragma unroll
                    for (int j = 0; j < 8; ++j)
                        acc[i][j] = fmaf(qa[i], tv[j], acc[i][j]);
            }
        }

        #pragma unroll
        for (int i = 0; i < 4; ++i)
            #pragma unroll
            for (int j = 0; j < 8; ++j) {
                int t = (j < 4) ? (tt4 + j) : (128 + tt4 + (j - 4));
                sD[tq4 + i][t] = fmaxf((qq[i] - 2.f * acc[i][j]) + t2[tbase + t], 0.f);
            }
        __syncthreads();

        if (tid < PQT) {
            for (int t = 0; t < PTT; ++t) {
                u32 d = __float_as_uint(sD[tid][t]);
                if (d < kth) {
                    int p = KNN - 1;
                    while (p > 0 && topk[tid][p - 1] > d) {
                        topk[tid][p] = topk[tid][p - 1];
                        --p;
                    }
                    topk[tid][p] = d;
                    kth = topk[tid][KNN - 1];
                }
            }
        }
    }
    if (tid < PQT) atomicMin(&seed[q0 + tid], kth);
}

__device__ __forceinline__ void stage_tile(const u16* __restrict__ Qh, const u16* __restrict__ Ql,
                                           const u16* __restrict__ Th, const u16* __restrict__ Tl,
                                           u16* base, int q0, int tb, int k0, int wid, int lane) {
    const int l4r = lane >> 2;
    const int l4c = (((lane & 3) ^ ((lane >> 3) & 3)) * 8);
    #pragma unroll
    for (int u = 0; u < 4; ++u) {
        const u16* P = (u == 0) ? Qh : (u == 1) ? Ql : (u == 2) ? Th : Tl;
        const int r0 = (u < 2) ? q0 : tb;
        const u16* g = P + (size_t)(r0 + wid * 16 + l4r) * DIM + k0 + l4c;
        gld16(g, base + u * 4096 + wid * 512);
    }
}

__launch_bounds__(512, 1)
__global__ void knn_mfma(const u16* __restrict__ Qh, const u16* __restrict__ Ql,
                         const u16* __restrict__ Th, const u16* __restrict__ Tl,
                         const float* __restrict__ q2, const float* __restrict__ t2,
                         const u32* __restrict__ seed, u64* __restrict__ cand) {
    __shared__ __align__(16) u16 tiles[3][16384];
    __shared__ u32 topkD[MQT][KNN + 1];
    __shared__ u16 topkI[MQT][KNN + 1];
    __shared__ u64 sbuf[MQT][SCAP];
    __shared__ u64 kth64[MQT];
    __shared__ u32 cnt[MQT];
    __shared__ float sQ2[MQT];
    __shared__ float sT2[MTT];
    __shared__ int againF;

    const int tid = threadIdx.x;
    const int lane = tid & 63;
    const int wid = tid >> 6;
    const int q0 = blockIdx.y * MQT;
    const int s0 = blockIdx.x * MSLICE;
    const int m_off = (wid >> 2) * 64;
    const int n_off = (wid & 3) * 32;
    const int swz = ((lane >> 1) & 3) << 3;

    for (int i = tid; i < MQT * (KNN + 1); i += 512) {
        ((u32*)topkD)[i] = 0xFFFFFFFFu;
        ((u16*)topkI)[i] = 0xFFFFu;
    }
    u64 seedkey = ~0ULL;
    if (tid < MQT) {
        seedkey = ((u64)seed[q0 + tid] + 1) << 16;
        kth64[tid] = seedkey;
        cnt[tid] = 0u;
        sQ2[tid] = q2[q0 + tid];
    }
    if (tid == 0) againF = 0;

    stage_tile(Qh, Ql, Th, Tl, tiles[0], q0, s0, 0, wid, lane);
    stage_tile(Qh, Ql, Th, Tl, tiles[1], q0, s0, MBK, wid, lane);
    __syncthreads();

    int cb = 0;
    #pragma unroll 1
    for (int chunk = 0; chunk < MSLICE / MTT; ++chunk) {
        const int tb = s0 + chunk * MTT;
        float16 acc[2];
        acc[0] = (float16)(0.0f);
        acc[1] = (float16)(0.0f);

        #pragma unroll 1
        for (int t = 0; t < DIM / MBK; ++t) {
            const int Tn = chunk * 16 + t + 2;
            const bool pf = (Tn < NTILES);
            if (pf) {
                int bn = cb + 2; if (bn >= 3) bn -= 3;
                stage_tile(Qh, Ql, Th, Tl, tiles[bn], q0,
                           s0 + (Tn >> 4) * MTT, (Tn & 15) * MBK, wid, lane);
            }
            const u16* sAh = tiles[cb];
            const u16* sAl = sAh + 4096;
            const u16* sBh = sAh + 8192;
            const u16* sBl = sAh + 12288;
            #pragma unroll
            for (int s = 0; s < 2; ++s) {
                const int kb = (s * 16 + (lane >> 5) * 8) ^ swz;
                short8 ah[2], al[2];
                #pragma unroll
                for (int mi = 0; mi < 2; ++mi) {
                    int row = m_off + mi * 32 + (lane & 31);
                    ah[mi] = *(const short8*)(const void*)&sAh[row * MBK + kb];
                    al[mi] = *(const short8*)(const void*)&sAl[row * MBK + kb];
                }
                int brow = n_off + (lane & 31);
                short8 bh = *(const short8*)(const void*)&sBh[brow * MBK + kb];
                short8 bl = *(const short8*)(const void*)&sBl[brow * MBK + kb];
                #pragma unroll
                for (int mi = 0; mi < 2; ++mi) {
                    acc[mi] = __builtin_amdgcn_mfma_f32_32x32x16_bf16(ah[mi], bh, acc[mi], 0, 0, 0);
                    acc[mi] = __builtin_amdgcn_mfma_f32_32x32x16_bf16(ah[mi], bl, acc[mi], 0, 0, 0);
                    acc[mi] = __builtin_amdgcn_mfma_f32_32x32x16_bf16(al[mi], bh, acc[mi], 0, 0, 0);
                }
            }
            if (pf) asm volatile("s_waitcnt vmcnt(4)" ::: "memory");
            else    asm volatile("s_waitcnt vmcnt(0)" ::: "memory");
            __builtin_amdgcn_s_barrier();
            __builtin_amdgcn_sched_barrier(0);
            ++cb; if (cb >= 3) cb = 0;
        }

        if (tid < MTT) sT2[tid] = t2[tb + tid];
        __syncthreads();
        const float t2r = sT2[n_off + (lane & 31)];
        const int tcol = n_off + (lane & 31);

        u32 mask = 0;
        for (;;) {
            #pragma unroll
            for (int mi = 0; mi < 2; ++mi) {
                #pragma unroll
                for (int r = 0; r < 16; ++r) {
                    const int bit = mi * 16 + r;
                    if ((mask >> bit) & 1) continue;
                    const int qrow = m_off + mi * 32 + (r & 3) + 8 * (r >> 2) + 4 * (lane >> 5);
                    float d = fmaxf(sQ2[qrow] - 2.0f * acc[mi][r] + t2r, 0.0f);
                    u64 key = ((u64)__float_as_uint(d) << 16) | (u64)(u32)(tb + tcol);
                    if (key < kth64[qrow]) {
                        u32 pos = atomicAdd(&cnt[qrow], 1u);
                        if (pos < SCAP) { sbuf[qrow][pos] = key; mask |= (1u << bit); }
                    }
                }
            }
            __syncthreads();
            if (tid < MQT) {
                u32 n = cnt[tid];
                u32 m = n < SCAP ? n : SCAP;
                for (u32 e = 0; e < m; ++e) {
                    u64 key = sbuf[tid][e];
                    u64 last = ((u64)topkD[tid][KNN - 1] << 16) | topkI[tid][KNN - 1];
                    if (key < last) {
                        int p = KNN - 1;
                        while (p > 0) {
                            u64 prev = ((u64)topkD[tid][p - 1] << 16) | topkI[tid][p - 1];
                            if (prev > key) {
                                topkD[tid][p] = topkD[tid][p - 1];
                                topkI[tid][p] = topkI[tid][p - 1];
                                --p;
                            } else break;
                        }
                        topkD[tid][p] = (u32)(key >> 16);
                        topkI[tid][p] = (u16)(key & 0xFFFF);
                    }
                }
                u64 last = ((u64)topkD[tid][KNN - 1] << 16) | topkI[tid][KNN - 1];
                kth64[tid] = last < seedkey ? last : seedkey;
                if (n > SCAP) againF = 1;
                cnt[tid] = 0u;
            }
            __syncthreads();
            int go = againF;
            __syncthreads();
            if (tid == 0) againF = 0;
            if (!go) break;
            __syncthreads();
        }
    }

    __syncthreads();
    for (int i = tid; i < MQT * KNN; i += 512) {
        int q = i >> 5, k = i & 31;
        u64 key = ((u64)topkD[q][k] << 16) | topkI[q][k];
        cand[((size_t)(q0 + q) * NS + blockIdx.x) * KNN + k] = key;
    }
}

__launch_bounds__(256, 4)
__global__ void knn_part(const float* __restrict__ Xq, const float* __restrict__ Xt,
                         const float* __restrict__ q2, const float* __restrict__ t2,
                         u64* __restrict__ cand) {
    __shared__ float sQ[KK][QT];
    __shared__ float sT[KK][TT];
    __shared__ u64 topk[QT][KNN];
    __shared__ u64 buf[QT][FCAP];
    __shared__ u64 kth64[QT];
    __shared__ u32 cnt[QT];
    __shared__ int againF;

    const int tid = threadIdx.x;
    const int q0 = blockIdx.x * QT;
    const int t0 = blockIdx.y * SLICE;
    const int tq4 = (tid >> 5) * 4;
    const int tt4 = (tid & 31) * 4;
    const int pg = tid & 63;
    const int kg = tid >> 6;
    const int qp = tid & 31;
    const int kq = tid >> 5;

    for (int i = tid; i < QT * KNN; i += 256) ((u64*)topk)[i] = ~0ULL;
    if (tid < QT) { kth64[tid] = ~0ULL; cnt[tid] = 0u; }
    if (tid == 0) againF = 0;

    float qq[4];
    #pragma unroll
    for (int i = 0; i < 4; ++i) qq[i] = q2[q0 + tq4 + i];

    #pragma unroll 1
    for (int chunk = 0; chunk < SLICE / TT; ++chunk) {
        const int tbase = t0 + chunk * TT;
        float acc[4][8];
        #pragma unroll
        for (int i = 0; i < 4; ++i)
            #pragma unroll
            for (int j = 0; j < 8; ++j) acc[i][j] = 0.f;

        #pragma unroll 1
        for (int k0 = 0; k0 < DIM; k0 += KK) {
            __syncthreads();
            {
                const float* Tp = Xt + (size_t)(tbase + pg * 4) * DIM + k0 + kg * 4;
                float4 r0 = *(const float4*)(Tp);
                float4 r1 = *(const float4*)(Tp + DIM);
                float4 r2 = *(const float4*)(Tp + 2 * DIM);
                float4 r3 = *(const float4*)(Tp + 3 * DIM);
                *(float4*)&sT[kg * 4 + 0][pg * 4] = make_float4(r0.x, r1.x, r2.x, r3.x);
                *(float4*)&sT[kg * 4 + 1][pg * 4] = make_float4(r0.y, r1.y, r2.y, r3.y);
                *(float4*)&sT[kg * 4 + 2][pg * 4] = make_float4(r0.z, r1.z, r2.z, r3.z);
                *(float4*)&sT[kg * 4 + 3][pg * 4] = make_float4(r0.w, r1.w, r2.w, r3.w);
            }
            {
                float2 v = *(const float2*)(Xq + (size_t)(q0 + qp) * DIM + k0 + kq * 2);
                sQ[kq * 2 + 0][qp] = v.x;
                sQ[kq * 2 + 1][qp] = v.y;
            }
            __syncthreads();
            #pragma unroll
            for (int k = 0; k < KK; ++k) {
                float4 qv = *(const float4*)&sQ[k][tq4];
                float4 ta = *(const float4*)&sT[k][tt4];
                float4 tb = *(const float4*)&sT[k][128 + tt4];
                float qa[4] = {qv.x, qv.y, qv.z, qv.w};
                float tv[8] = {ta.x, ta.y, ta.z, ta.w, tb.x, tb.y, tb.z, tb.w};
                #pragma unroll
                for (int i = 0; i < 4; ++i)
                    #pragma unroll
                    for (int j = 0; j < 8; ++j)
                        acc[i][j] = fmaf(qa[i], tv[j], acc[i][j]);
            }
        }

        float t2v[8];
        #pragma unroll
        for (int j = 0; j < 4; ++j) {
            t2v[j]     = t2[tbase + tt4 + j];
            t2v[4 + j] = t2[tbase + 128 + tt4 + j];
        }
        #pragma unroll
        for (int i = 0; i < 4; ++i)
            #pragma unroll
            for (int j = 0; j < 8; ++j)
                acc[i][j] = fmaxf((qq[i] - 2.f * acc[i][j]) + t2v[j], 0.f);

        unsigned mask = 0;
        for (;;) {
            u64 kv[4];
            #pragma unroll
            for (int i = 0; i < 4; ++i) kv[i] = kth64[tq4 + i];
            #pragma unroll
            for (int i = 0; i < 4; ++i) {
                #pragma unroll
                for (int j = 0; j < 8; ++j) {
                    unsigned b = 1u << (i * 8 + j);
                    if (mask & b) continue;
                    int tloc = (j < 4) ? (tt4 + j) : (128 + tt4 + (j - 4));
                    u64 key = ((u64)__float_as_uint(acc[i][j]) << 16) |
                              (u64)(unsigned)(tbase + tloc);
                    if (key < kv[i]) {
                        unsigned pos = atomicAdd(&cnt[tq4 + i], 1u);
                        if (pos < FCAP) { buf[tq4 + i][pos] = key; mask |= b; }
                    }
                }
            }
            __syncthreads();
            if (tid < QT) {
                unsigned n = cnt[tid];
                unsigned m = n < FCAP ? n : FCAP;
                for (unsigned e = 0; e < m; ++e) {
                    u64 key = buf[tid][e];
                    if (key < topk[tid][KNN - 1]) {
                        int p = KNN - 1;
                        while (p > 0 && topk[tid][p - 1] > key) {
                            topk[tid][p] = topk[tid][p - 1];
                            --p;
                        }
                        topk[tid][p] = key;
                    }
                }
                kth64[tid] = topk[tid][KNN - 1];
                if (n > FCAP) againF = 1;
                cnt[tid] = 0u;
            }
            __syncthreads();
            int go = againF;
            __syncthreads();
            if (tid == 0) againF = 0;
            if (!go) break;
            __syncthreads();
        }
    }

    __syncthreads();
    for (int i = tid; i < QT * KNN; i += 256) {
        int q = i >> 5, k = i & 31;
        cand[((size_t)(q0 + q) * NS + blockIdx.y) * KNN + k] = topk[q][k];
    }
}

__global__ void knn_merge(const u64* __restrict__ cand,
                          const int* __restrict__ y_train, int* __restrict__ out) {
    __shared__ u64 keys[NS * KNN];
    __shared__ u64 top[KNN];
    __shared__ int counts[NC];
    int q = blockIdx.x;
    for (int i = threadIdx.x; i < NS * KNN; i += 64)
        keys[i] = cand[(size_t)q * NS * KNN + i];
    for (int i = threadIdx.x; i < NC; i += 64) counts[i] = 0;
    if (threadIdx.x < KNN) top[threadIdx.x] = ~0ULL;
    __syncthreads();

    if (threadIdx.x == 0) {
        for (int s = 0; s < NS; ++s) {
            for (int j = 0; j < KNN; ++j) {
                u64 key = keys[s * KNN + j];
                if (key >= top[KNN - 1]) break;
                int p = KNN - 1;
                while (p > 0 && top[p - 1] > key) { top[p] = top[p - 1]; --p; }
                top[p] = key;
            }
        }
        for (int k = 0; k < KNN; ++k) {
            int idx = (int)(top[k] & 0xFFFF);
            counts[y_train[idx]]++;
        }
        int bestc = counts[0], bestl = 0;
        for (int c = 1; c < NC; ++c)
            if (counts[c] > bestc) { bestc = counts[c]; bestl = c; }
        out[q] = bestl;
    }
}

extern "C" void kernel_launch(void* const* d_in, const int* in_sizes, int n_in,
                              void* d_out, int out_size, void* d_ws, size_t ws_size,
                              hipStream_t stream) {
    const float* Xq = (const float*)d_in[0];   // [2048, 512]
    const float* Xt = (const float*)d_in[1];   // [65536, 512]
    const int*   y  = (const int*)d_in[2];     // [65536]
    int* out = (int*)d_out;                    // [2048] int32

    float* t2 = (float*)d_ws;                                   // 256 KB
    float* q2 = t2 + NT;                                        // 8 KB
    u64* cand = (u64*)(q2 + NQ);                                // 16.8 MB (fallback paths)
    u32* seed = (u32*)(cand + (size_t)NQ * NS * KNN);           // 8 KB
    u16* Qh = (u16*)(seed + NQ);                                // 2 MB
    u16* Ql = Qh + (size_t)NQ * DIM;                            // 2 MB
    u16* Th = Ql + (size_t)NQ * DIM;                            // 64 MB
    u16* Tl = Th + (size_t)NT * DIM;                            // 64 MB
    u64* glist = (u64*)(Tl + (size_t)NT * DIM);                 // 64 MB (filter path)
    u32* gcnt  = (u32*)(glist + (size_t)NQ * GCAP);             // 8 KB
    float* Dpre = (float*)glist;                                // 16 MB, aliases glist (dead before gemm)

    const size_t need = (size_t)(NT + NQ) * 4
                      + (size_t)NQ * NS * KNN * 8
                      + (size_t)NQ * 4
                      + 2 * ((size_t)NQ * DIM + (size_t)NT * DIM) * 2;  // ~148.3 MB
    const bool use_mfma = ws_size >= need;
    const bool use_filter = ws_size >= need + (size_t)NQ * GCAP * 8 + (size_t)NQ * 4;  // +64 MB

    norm_kernel<<<NT / 4, 256, 0, stream>>>(Xt, t2, NT);
    norm_kernel<<<NQ / 4, 256, 0, stream>>>(Xq, q2, NQ);
    if (use_mfma && use_filter) {
        split_kernel<<<(NQ * DIM / 4 + 255) / 256, 256, 0, stream>>>(Xq, Qh, Ql, NQ * DIM / 4);
        split_kernel<<<(NT * DIM / 4 + 255) / 256, 256, 0, stream>>>(Xt, Th, Tl, NT * DIM / 4);
        knn_pre<<<dim3(NQ / PQT, NTPRE / PSLICE), 256, 0, stream>>>(Xq, Xt, q2, t2, Dpre);
        seed_topk<<<NQ, 64, 0, stream>>>(Dpre, seed);
        hipMemsetAsync(gcnt, 0, NQ * sizeof(u32), stream);
        gemm_filter<<<dim3(NT / 128, NQ / 128), 256, 0, stream>>>(
            Qh, Ql, Th, Tl, q2, t2, seed, gcnt, glist);
        knn_topk<<<NQ, 64, 0, stream>>>(glist, gcnt, y, out);
    } else if (use_mfma) {
        hipMemsetAsync(seed, 0xFF, NQ * sizeof(u32), stream);
        split_kernel<<<(NQ * DIM / 4 + 255) / 256, 256, 0, stream>>>(Xq, Qh, Ql, NQ * DIM / 4);
        split_kernel<<<(NT * DIM / 4 + 255) / 256, 256, 0, stream>>>(Xt, Th, Tl, NT * DIM / 4);
        knn_prepass<<<dim3(NQ / PQT, NTPRE / PSLICE), 256, 0, stream>>>(Xq, Xt, q2, t2, seed);
        knn_mfma<<<dim3(NT / MSLICE, NQ / MQT), 512, 0, stream>>>(Qh, Ql, Th, Tl, q2, t2, seed, cand);
        knn_merge<<<NQ, 64, 0, stream>>>(cand, y, out);
    } else {
        knn_part<<<dim3(NQ / QT, NS), 256, 0, stream>>>(Xq, Xt, q2, t2, cand);
        knn_merge<<<NQ, 64, 0, stream>>>(cand, y, out);
    }
}

// Round 7
// 1263.101 us; speedup vs baseline: 2.8762x; 1.7589x over previous
//
#include <hip/hip_runtime.h>
#include <hip/hip_bf16.h>
#include <stdint.h>

typedef unsigned long long u64;
typedef unsigned int u32;
typedef unsigned short u16;
typedef __attribute__((ext_vector_type(8))) short short8;
typedef __attribute__((ext_vector_type(16))) float float16;

#define NQ 2048
#define NT 65536
#define DIM 512
#define KNN 32
#define NC 100
#define NS 32               // slices (fallback paths), cand[q][slice][k]

// ---- fallback (R2) params ----
#define QT 32
#define SLICE (NT / NS)     // 2048
#define TT 256
#define KK 16
#define FCAP 32

// ---- prepass params (fp32, trains 0..2047 subsample) ----
#define PQT 32
#define PTT 256
#define PSLICE 512
#define NTPRE 2048

// ---- fused-mfma fallback params (R4, proven) ----
#define MQT 128
#define MTT 128
#define MBK 32
#define MSLICE 2048
#define SCAP 16
#define NTILES 256

// ---- filter-path params (R6, proven) ----
#define GCAP 4096           // per-query candidate capacity; exact-2048 seed admits ~1024±180 (17 sigma)

// ---------------- row-norm kernel ----------------
__global__ void norm_kernel(const float* __restrict__ X, float* __restrict__ out, int nrows) {
    int row = blockIdx.x * 4 + (threadIdx.x >> 6);
    int lane = threadIdx.x & 63;
    if (row >= nrows) return;
    const float4* p = (const float4*)(X + (size_t)row * DIM);
    float4 a = p[lane];
    float4 b = p[lane + 64];
    float s = a.x*a.x + a.y*a.y + a.z*a.z + a.w*a.w
            + b.x*b.x + b.y*b.y + b.z*b.z + b.w*b.w;
    #pragma unroll
    for (int off = 32; off > 0; off >>= 1) s += __shfl_down(s, off, 64);
    if (lane == 0) out[row] = s;
}

// ---------------- bf16 hi/lo split ----------------
__global__ void split_kernel(const float* __restrict__ X, u16* __restrict__ H,
                             u16* __restrict__ L, int n4) {
    int i = blockIdx.x * 256 + threadIdx.x;
    if (i >= n4) return;
    float4 v = ((const float4*)X)[i];
    float f[4] = {v.x, v.y, v.z, v.w};
    u16 hh[4], ll[4];
    #pragma unroll
    for (int j = 0; j < 4; ++j) {
        union { __hip_bfloat16 b; u16 u; } cv;
        cv.b = __float2bfloat16(f[j]);
        hh[j] = cv.u;
        float hf = __bfloat162float(cv.b);
        cv.b = __float2bfloat16(f[j] - hf);
        ll[j] = cv.u;
    }
    ((ushort4*)H)[i] = make_ushort4(hh[0], hh[1], hh[2], hh[3]);
    ((ushort4*)L)[i] = make_ushort4(ll[0], ll[1], ll[2], ll[3]);
}

// ---------------- knn_pre: fp32 distances for trains 0..2047, written to Dpre --------------
// grid: (NQ/PQT=64, NTPRE/PSLICE=4), 256 thr. Pure compute+store; no selection protocol.
__launch_bounds__(256, 2)
__global__ void knn_pre(const float* __restrict__ Xq, const float* __restrict__ Xt,
                        const float* __restrict__ q2, const float* __restrict__ t2,
                        float* __restrict__ Dpre) {
    __shared__ float sQ[KK][PQT];
    __shared__ float sT[KK][PTT];

    const int tid = threadIdx.x;
    const int q0 = blockIdx.x * PQT;
    const int t0p = blockIdx.y * PSLICE;
    const int tq4 = (tid >> 5) * 4;
    const int tt4 = (tid & 31) * 4;
    const int pg = tid & 63;
    const int kg = tid >> 6;
    const int qp = tid & 31;
    const int kq = tid >> 5;

    float qq[4];
    #pragma unroll
    for (int i = 0; i < 4; ++i) qq[i] = q2[q0 + tq4 + i];

    #pragma unroll 1
    for (int chunk = 0; chunk < PSLICE / PTT; ++chunk) {
        const int tbase = t0p + chunk * PTT;
        float acc[4][8];
        #pragma unroll
        for (int i = 0; i < 4; ++i)
            #pragma unroll
            for (int j = 0; j < 8; ++j) acc[i][j] = 0.f;

        #pragma unroll 1
        for (int k0 = 0; k0 < DIM; k0 += KK) {
            __syncthreads();   // protects sQ/sT reuse
            {
                const float* Tp = Xt + (size_t)(tbase + pg * 4) * DIM + k0 + kg * 4;
                float4 r0 = *(const float4*)(Tp);
                float4 r1 = *(const float4*)(Tp + DIM);
                float4 r2 = *(const float4*)(Tp + 2 * DIM);
                float4 r3 = *(const float4*)(Tp + 3 * DIM);
                *(float4*)&sT[kg * 4 + 0][pg * 4] = make_float4(r0.x, r1.x, r2.x, r3.x);
                *(float4*)&sT[kg * 4 + 1][pg * 4] = make_float4(r0.y, r1.y, r2.y, r3.y);
                *(float4*)&sT[kg * 4 + 2][pg * 4] = make_float4(r0.z, r1.z, r2.z, r3.z);
                *(float4*)&sT[kg * 4 + 3][pg * 4] = make_float4(r0.w, r1.w, r2.w, r3.w);
            }
            {
                float2 v = *(const float2*)(Xq + (size_t)(q0 + qp) * DIM + k0 + kq * 2);
                sQ[kq * 2 + 0][qp] = v.x;
                sQ[kq * 2 + 1][qp] = v.y;
            }
            __syncthreads();
            #pragma unroll
            for (int k = 0; k < KK; ++k) {
                float4 qv = *(const float4*)&sQ[k][tq4];
                float4 ta = *(const float4*)&sT[k][tt4];
                float4 tb = *(const float4*)&sT[k][128 + tt4];
                float qa[4] = {qv.x, qv.y, qv.z, qv.w};
                float tv[8] = {ta.x, ta.y, ta.z, ta.w, tb.x, tb.y, tb.z, tb.w};
                #pragma unroll
                for (int i = 0; i < 4; ++i)
                    #pragma unroll
                    for (int j = 0; j < 8; ++j)
                        acc[i][j] = fmaf(qa[i], tv[j], acc[i][j]);
            }
        }

        float t2v[8];
        #pragma unroll
        for (int j = 0; j < 4; ++j) {
            t2v[j]     = t2[tbase + tt4 + j];
            t2v[4 + j] = t2[tbase + 128 + tt4 + j];
        }
        #pragma unroll
        for (int i = 0; i < 4; ++i) {
            float4 lo, hi;
            lo.x = fmaxf(qq[i] - 2.f * acc[i][0] + t2v[0], 0.f);
            lo.y = fmaxf(qq[i] - 2.f * acc[i][1] + t2v[1], 0.f);
            lo.z = fmaxf(qq[i] - 2.f * acc[i][2] + t2v[2], 0.f);
            lo.w = fmaxf(qq[i] - 2.f * acc[i][3] + t2v[3], 0.f);
            hi.x = fmaxf(qq[i] - 2.f * acc[i][4] + t2v[4], 0.f);
            hi.y = fmaxf(qq[i] - 2.f * acc[i][5] + t2v[5], 0.f);
            hi.z = fmaxf(qq[i] - 2.f * acc[i][6] + t2v[6], 0.f);
            hi.w = fmaxf(qq[i] - 2.f * acc[i][7] + t2v[7], 0.f);
            *(float4*)&Dpre[(size_t)(q0 + tq4 + i) * NTPRE + tbase + tt4] = lo;
            *(float4*)&Dpre[(size_t)(q0 + tq4 + i) * NTPRE + tbase + 128 + tt4] = hi;
        }
    }
}

// ---------------- seed_topk: exact 32nd-smallest of Dpre row -> seed[q] -------------------
// grid: NQ blocks x 64 threads (one wave per query). Per-lane sorted-32 in LDS (padded rows),
// then 32x wave-min extraction; the 32nd extracted value is the seed.
__launch_bounds__(64)
__global__ void seed_topk(const float* __restrict__ Dpre, u32* __restrict__ seed) {
    __shared__ u64 ll[64][KNN + 1];   // pad: stride 33 u64 -> 2-way banks only
    const int q = blockIdx.x;
    const int lane = threadIdx.x;
    #pragma unroll
    for (int j = 0; j <= KNN; ++j) ll[lane][j] = ~0ULL;
    const float* src = Dpre + (size_t)q * NTPRE;
    u64 kth = ~0ULL;
    for (int i = lane; i < NTPRE; i += 64) {
        u64 key = (u64)__float_as_uint(src[i]);
        if (key < kth) {
            int p = KNN - 1;
            while (p > 0 && ll[lane][p - 1] > key) { ll[lane][p] = ll[lane][p - 1]; --p; }
            ll[lane][p] = key;
            kth = ll[lane][KNN - 1];
        }
    }
    __syncthreads();
    int ptr = 0;
    u64 cur = ll[lane][0];
    u64 m = 0;
    for (int it = 0; it < KNN; ++it) {
        m = cur;
        #pragma unroll
        for (int off = 32; off > 0; off >>= 1) {
            u64 o = __shfl_xor(m, off, 64);
            m = (o < m) ? o : m;
        }
        u64 got = __ballot(cur == m);
        int w = __ffsll(got) - 1;
        if (lane == w) { ++ptr; cur = (ptr < KNN) ? ll[lane][ptr] : ~0ULL; }
    }
    if (lane == 0) seed[q] = (u32)m;   // 32nd smallest dist bits (exact over 2048 subsample)
}

// ---------------- async global->LDS 16B ----------------
__device__ __forceinline__ void gld16(const void* g, void* l) {
    __builtin_amdgcn_global_load_lds(
        (const __attribute__((address_space(1))) u32*)g,
        (__attribute__((address_space(3))) u32*)l, 16, 0, 0);
}

// ---------------- gemm_filter: m97-style 128x128 GEMM + seed-filter push epilogue ---------
// R7 grid TRANSPOSE: (x=NQ/128=16, y=NT/128=512), x fastest. 16 consecutive blocks now share
// the SAME 256 KB T-tile (each XCD L2 fills it once, 2 resident blocks reuse); Q (4 MB) is
// permanently L2/L3-resident. Ideal HBM traffic ~150 MB vs R6's measured 1.1 GB (8x overfetch
// from 16 q-strips each streaming the whole 128 MB T panel). 4 blocks/CU for latency overlap.
// Survivors (d_bits <= seed+margin, ~2 per (q,128t)) push straight to glist[q] via one atomic.
__launch_bounds__(256, 4)
__global__ void gemm_filter(const u16* __restrict__ Qh, const u16* __restrict__ Ql,
                            const u16* __restrict__ Th, const u16* __restrict__ Tl,
                            const float* __restrict__ q2, const float* __restrict__ t2,
                            const u32* __restrict__ seed,
                            u32* __restrict__ gcnt, u64* __restrict__ glist) {
    __shared__ __align__(16) u16 tile[4][4096];   // Ah,Al,Bh,Bl : [128][32] each (32 KB)
    __shared__ float sQ2L[128];
    __shared__ float sT2L[128];
    __shared__ u32 sSeed[128];

    const int tid = threadIdx.x;
    const int lane = tid & 63;
    const int wid = tid >> 6;             // 0..3
    const int q0g = blockIdx.x * 128;     // query base  (x: fast-varying -> shared T tile)
    const int tb  = blockIdx.y * 128;     // train base  (y: slow-varying)
    const int m_off = (wid >> 1) * 64;
    const int n_off = (wid & 1) * 64;
    const int swz = ((lane >> 1) & 3) << 3;
    const int l4r = lane >> 2;
    const int l4c = (((lane & 3) ^ ((lane >> 3) & 3)) * 8);

    if (tid < 128) {
        sQ2L[tid] = q2[q0g + tid];
        sT2L[tid] = t2[tb + tid];
        sSeed[tid] = seed[q0g + tid] + 256u;   // admission threshold (+ulp margin)
    }

    float16 acc[2][2];
    acc[0][0] = (float16)(0.0f); acc[0][1] = (float16)(0.0f);
    acc[1][0] = (float16)(0.0f); acc[1][1] = (float16)(0.0f);

    #pragma unroll 1
    for (int k0 = 0; k0 < DIM; k0 += MBK) {
        __syncthreads();   // prev compute done (first iter: sQ2L/sT2L/sSeed staged)
        #pragma unroll
        for (int u = 0; u < 4; ++u) {
            const u16* P = (u == 0) ? Qh : (u == 1) ? Ql : (u == 2) ? Th : Tl;
            const int rb = (u < 2) ? q0g : tb;
            #pragma unroll
            for (int j = 0; j < 2; ++j) {
                const int rg = j * 64 + wid * 16;
                gld16(P + (size_t)(rb + rg + l4r) * DIM + k0 + l4c,
                      (u16*)tile[u] + rg * 32);
            }
        }
        __syncthreads();   // tiles ready

        #pragma unroll
        for (int s = 0; s < 2; ++s) {
            const int kb = (s * 16 + (lane >> 5) * 8) ^ swz;
            short8 ah[2], al[2], bh[2], bl[2];
            #pragma unroll
            for (int mi = 0; mi < 2; ++mi) {
                int row = m_off + mi * 32 + (lane & 31);
                ah[mi] = *(const short8*)(const void*)&tile[0][row * 32 + kb];
                al[mi] = *(const short8*)(const void*)&tile[1][row * 32 + kb];
            }
            #pragma unroll
            for (int nj = 0; nj < 2; ++nj) {
                int row = n_off + nj * 32 + (lane & 31);
                bh[nj] = *(const short8*)(const void*)&tile[2][row * 32 + kb];
                bl[nj] = *(const short8*)(const void*)&tile[3][row * 32 + kb];
            }
            #pragma unroll
            for (int mi = 0; mi < 2; ++mi)
                #pragma unroll
                for (int nj = 0; nj < 2; ++nj) {
                    acc[mi][nj] = __builtin_amdgcn_mfma_f32_32x32x16_bf16(ah[mi], bh[nj], acc[mi][nj], 0, 0, 0);
                    acc[mi][nj] = __builtin_amdgcn_mfma_f32_32x32x16_bf16(ah[mi], bl[nj], acc[mi][nj], 0, 0, 0);
                    acc[mi][nj] = __builtin_amdgcn_mfma_f32_32x32x16_bf16(al[mi], bh[nj], acc[mi][nj], 0, 0, 0);
                }
        }
    }

    // epilogue: rare filtered push (frag map: col=lane&31, row=(r&3)+8*(r>>2)+4*(lane>>5))
    #pragma unroll
    for (int mi = 0; mi < 2; ++mi)
        #pragma unroll
        for (int nj = 0; nj < 2; ++nj) {
            const int tcol_l = n_off + nj * 32 + (lane & 31);
            const float t2v = sT2L[tcol_l];
            #pragma unroll
            for (int r = 0; r < 16; ++r) {
                const int qrow_l = m_off + mi * 32 + (r & 3) + 8 * (r >> 2) + 4 * (lane >> 5);
                float d = fmaxf(sQ2L[qrow_l] - 2.0f * acc[mi][nj][r] + t2v, 0.0f);
                if (__float_as_uint(d) <= sSeed[qrow_l]) {
                    const int q = q0g + qrow_l;
                    u32 pos = atomicAdd(&gcnt[q], 1u);
                    if (pos < GCAP)
                        glist[(size_t)q * GCAP + pos] =
                            ((u64)__float_as_uint(d) << 16) | (u64)(u32)(tb + tcol_l);
                }
            }
        }
}

// ---------------- knn_topk: exact top-32 over candidate list + vote -> out ----------------
// grid: NQ blocks x 64 threads (one wave per query). n ~ 1024 (seed guarantees n >= 32).
__launch_bounds__(64)
__global__ void knn_topk(const u64* __restrict__ glist, const u32* __restrict__ gcnt,
                         const int* __restrict__ y_train, int* __restrict__ out) {
    __shared__ u64 ll[64][KNN + 1];
    __shared__ u64 fin[KNN];
    __shared__ int counts[NC];
    const int q = blockIdx.x;
    const int lane = threadIdx.x;
    #pragma unroll
    for (int j = 0; j <= KNN; ++j) ll[lane][j] = ~0ULL;
    for (int i = lane; i < NC; i += 64) counts[i] = 0;
    u32 n = gcnt[q]; if (n > GCAP) n = GCAP;
    const u64* src = glist + (size_t)q * GCAP;
    u64 kth = ~0ULL;
    for (u32 i = lane; i < n; i += 64) {
        u64 key = src[i];
        if (key < kth) {
            int p = KNN - 1;
            while (p > 0 && ll[lane][p - 1] > key) { ll[lane][p] = ll[lane][p - 1]; --p; }
            ll[lane][p] = key;
            kth = ll[lane][KNN - 1];
        }
    }
    __syncthreads();
    int ptr = 0;
    u64 cur = ll[lane][0];
    for (int it = 0; it < KNN; ++it) {
        u64 m = cur;
        #pragma unroll
        for (int off = 32; off > 0; off >>= 1) {
            u64 o = __shfl_xor(m, off, 64);
            m = (o < m) ? o : m;
        }
        u64 got = __ballot(cur == m);
        int w = __ffsll(got) - 1;
        if (lane == 0) fin[it] = m;
        if (lane == w) { ++ptr; cur = (ptr < KNN) ? ll[lane][ptr] : ~0ULL; }
    }
    __syncthreads();
    if (lane < KNN) {
        int idx = (int)(fin[lane] & 0xFFFF);
        atomicAdd(&counts[y_train[idx]], 1);
    }
    __syncthreads();
    if (lane == 0) {
        int bestc = counts[0], bestl = 0;
        for (int c = 1; c < NC; ++c)
            if (counts[c] > bestc) { bestc = counts[c]; bestl = c; }
        out[q] = bestl;
    }
}

// ================= fallback machinery (R4 fused path + fp32 path), proven =================

// old prepass with min-of-4x512 seed (fallback fused path only)
__launch_bounds__(256, 2)
__global__ void knn_prepass(const float* __restrict__ Xq, const float* __restrict__ Xt,
                            const float* __restrict__ q2, const float* __restrict__ t2,
                            u32* __restrict__ seed) {
    __shared__ float sQ[KK][PQT];
    __shared__ float sT[KK][PTT];
    __shared__ float sD[PQT][PTT + 1];
    __shared__ u32 topk[PQT][KNN + 1];

    const int tid = threadIdx.x;
    const int q0 = blockIdx.x * PQT;
    const int t0p = blockIdx.y * PSLICE;
    const int tq4 = (tid >> 5) * 4;
    const int tt4 = (tid & 31) * 4;
    const int pg = tid & 63;
    const int kg = tid >> 6;
    const int qp = tid & 31;
    const int kq = tid >> 5;

    for (int i = tid; i < PQT * (KNN + 1); i += 256) ((u32*)topk)[i] = 0xFFFFFFFFu;
    u32 kth = 0xFFFFFFFFu;

    float qq[4];
    #pragma unroll
    for (int i = 0; i < 4; ++i) qq[i] = q2[q0 + tq4 + i];

    #pragma unroll 1
    for (int chunk = 0; chunk < PSLICE / PTT; ++chunk) {
        const int tbase = t0p + chunk * PTT;
        float acc[4][8];
        #pragma unroll
        for (int i = 0; i < 4; ++i)
            #pragma unroll
            for (int j = 0; j < 8; ++j) acc[i][j] = 0.f;

        #pragma unroll 1
        for (int k0 = 0; k0 < DIM; k0 += KK) {
            __syncthreads();
            {
                const float* Tp = Xt + (size_t)(tbase + pg * 4) * DIM + k0 + kg * 4;
                float4 r0 = *(const float4*)(Tp);
                float4 r1 = *(const float4*)(Tp + DIM);
                float4 r2 = *(const float4*)(Tp + 2 * DIM);
                float4 r3 = *(const float4*)(Tp + 3 * DIM);
                *(float4*)&sT[kg * 4 + 0][pg * 4] = make_float4(r0.x, r1.x, r2.x, r3.x);
                *(float4*)&sT[kg * 4 + 1][pg * 4] = make_float4(r0.y, r1.y, r2.y, r3.y);
                *(float4*)&sT[kg * 4 + 2][pg * 4] = make_float4(r0.z, r1.z, r2.z, r3.z);
                *(float4*)&sT[kg * 4 + 3][pg * 4] = make_float4(r0.w, r1.w, r2.w, r3.w);
            }
            {
                float2 v = *(const float2*)(Xq + (size_t)(q0 + qp) * DIM + k0 + kq * 2);
                sQ[kq * 2 + 0][qp] = v.x;
                sQ[kq * 2 + 1][qp] = v.y;
            }
            __syncthreads();
            #pragma unroll
            for (int k = 0; k < KK; ++k) {
                float4 qv = *(const float4*)&sQ[k][tq4];
                float4 ta = *(const float4*)&sT[k][tt4];
                float4 tb = *(const float4*)&sT[k][128 + tt4];
                float qa[4] = {qv.x, qv.y, qv.z, qv.w};
                float tv[8] = {ta.x, ta.y, ta.z, ta.w, tb.x, tb.y, tb.z, tb.w};
                #pragma unroll
                for (int i = 0; i < 4; ++i)
                    #pragma unroll
                    for (int j = 0; j < 8; ++j)
                        acc[i][j] = fmaf(qa[i], tv[j], acc[i][j]);
            }
        }

        #pragma unroll
        for (int i = 0; i < 4; ++i)
            #pragma unroll
            for (int j = 0; j < 8; ++j) {
                int t = (j < 4) ? (tt4 + j) : (128 + tt4 + (j - 4));
                sD[tq4 + i][t] = fmaxf((qq[i] - 2.f * acc[i][j]) + t2[tbase + t], 0.f);
            }
        __syncthreads();

        if (tid < PQT) {
            for (int t = 0; t < PTT; ++t) {
                u32 d = __float_as_uint(sD[tid][t]);
                if (d < kth) {
                    int p = KNN - 1;
                    while (p > 0 && topk[tid][p - 1] > d) {
                        topk[tid][p] = topk[tid][p - 1];
                        --p;
                    }
                    topk[tid][p] = d;
                    kth = topk[tid][KNN - 1];
                }
            }
        }
    }
    if (tid < PQT) atomicMin(&seed[q0 + tid], kth);
}

__device__ __forceinline__ void stage_tile(const u16* __restrict__ Qh, const u16* __restrict__ Ql,
                                           const u16* __restrict__ Th, const u16* __restrict__ Tl,
                                           u16* base, int q0, int tb, int k0, int wid, int lane) {
    const int l4r = lane >> 2;
    const int l4c = (((lane & 3) ^ ((lane >> 3) & 3)) * 8);
    #pragma unroll
    for (int u = 0; u < 4; ++u) {
        const u16* P = (u == 0) ? Qh : (u == 1) ? Ql : (u == 2) ? Th : Tl;
        const int r0 = (u < 2) ? q0 : tb;
        const u16* g = P + (size_t)(r0 + wid * 16 + l4r) * DIM + k0 + l4c;
        gld16(g, base + u * 4096 + wid * 512);
    }
}

__launch_bounds__(512, 1)
__global__ void knn_mfma(const u16* __restrict__ Qh, const u16* __restrict__ Ql,
                         const u16* __restrict__ Th, const u16* __restrict__ Tl,
                         const float* __restrict__ q2, const float* __restrict__ t2,
                         const u32* __restrict__ seed, u64* __restrict__ cand) {
    __shared__ __align__(16) u16 tiles[3][16384];
    __shared__ u32 topkD[MQT][KNN + 1];
    __shared__ u16 topkI[MQT][KNN + 1];
    __shared__ u64 sbuf[MQT][SCAP];
    __shared__ u64 kth64[MQT];
    __shared__ u32 cnt[MQT];
    __shared__ float sQ2[MQT];
    __shared__ float sT2[MTT];
    __shared__ int againF;

    const int tid = threadIdx.x;
    const int lane = tid & 63;
    const int wid = tid >> 6;
    const int q0 = blockIdx.y * MQT;
    const int s0 = blockIdx.x * MSLICE;
    const int m_off = (wid >> 2) * 64;
    const int n_off = (wid & 3) * 32;
    const int swz = ((lane >> 1) & 3) << 3;

    for (int i = tid; i < MQT * (KNN + 1); i += 512) {
        ((u32*)topkD)[i] = 0xFFFFFFFFu;
        ((u16*)topkI)[i] = 0xFFFFu;
    }
    u64 seedkey = ~0ULL;
    if (tid < MQT) {
        seedkey = ((u64)seed[q0 + tid] + 1) << 16;
        kth64[tid] = seedkey;
        cnt[tid] = 0u;
        sQ2[tid] = q2[q0 + tid];
    }
    if (tid == 0) againF = 0;

    stage_tile(Qh, Ql, Th, Tl, tiles[0], q0, s0, 0, wid, lane);
    stage_tile(Qh, Ql, Th, Tl, tiles[1], q0, s0, MBK, wid, lane);
    __syncthreads();

    int cb = 0;
    #pragma unroll 1
    for (int chunk = 0; chunk < MSLICE / MTT; ++chunk) {
        const int tb = s0 + chunk * MTT;
        float16 acc[2];
        acc[0] = (float16)(0.0f);
        acc[1] = (float16)(0.0f);

        #pragma unroll 1
        for (int t = 0; t < DIM / MBK; ++t) {
            const int Tn = chunk * 16 + t + 2;
            const bool pf = (Tn < NTILES);
            if (pf) {
                int bn = cb + 2; if (bn >= 3) bn -= 3;
                stage_tile(Qh, Ql, Th, Tl, tiles[bn], q0,
                           s0 + (Tn >> 4) * MTT, (Tn & 15) * MBK, wid, lane);
            }
            const u16* sAh = tiles[cb];
            const u16* sAl = sAh + 4096;
            const u16* sBh = sAh + 8192;
            const u16* sBl = sAh + 12288;
            #pragma unroll
            for (int s = 0; s < 2; ++s) {
                const int kb = (s * 16 + (lane >> 5) * 8) ^ swz;
                short8 ah[2], al[2];
                #pragma unroll
                for (int mi = 0; mi < 2; ++mi) {
                    int row = m_off + mi * 32 + (lane & 31);
                    ah[mi] = *(const short8*)(const void*)&sAh[row * MBK + kb];
                    al[mi] = *(const short8*)(const void*)&sAl[row * MBK + kb];
                }
                int brow = n_off + (lane & 31);
                short8 bh = *(const short8*)(const void*)&sBh[brow * MBK + kb];
                short8 bl = *(const short8*)(const void*)&sBl[brow * MBK + kb];
                #pragma unroll
                for (int mi = 0; mi < 2; ++mi) {
                    acc[mi] = __builtin_amdgcn_mfma_f32_32x32x16_bf16(ah[mi], bh, acc[mi], 0, 0, 0);
                    acc[mi] = __builtin_amdgcn_mfma_f32_32x32x16_bf16(ah[mi], bl, acc[mi], 0, 0, 0);
                    acc[mi] = __builtin_amdgcn_mfma_f32_32x32x16_bf16(al[mi], bh, acc[mi], 0, 0, 0);
                }
            }
            if (pf) asm volatile("s_waitcnt vmcnt(4)" ::: "memory");
            else    asm volatile("s_waitcnt vmcnt(0)" ::: "memory");
            __builtin_amdgcn_s_barrier();
            __builtin_amdgcn_sched_barrier(0);
            ++cb; if (cb >= 3) cb = 0;
        }

        if (tid < MTT) sT2[tid] = t2[tb + tid];
        __syncthreads();
        const float t2r = sT2[n_off + (lane & 31)];
        const int tcol = n_off + (lane & 31);

        u32 mask = 0;
        for (;;) {
            #pragma unroll
            for (int mi = 0; mi < 2; ++mi) {
                #pragma unroll
                for (int r = 0; r < 16; ++r) {
                    const int bit = mi * 16 + r;
                    if ((mask >> bit) & 1) continue;
                    const int qrow = m_off + mi * 32 + (r & 3) + 8 * (r >> 2) + 4 * (lane >> 5);
                    float d = fmaxf(sQ2[qrow] - 2.0f * acc[mi][r] + t2r, 0.0f);
                    u64 key = ((u64)__float_as_uint(d) << 16) | (u64)(u32)(tb + tcol);
                    if (key < kth64[qrow]) {
                        u32 pos = atomicAdd(&cnt[qrow], 1u);
                        if (pos < SCAP) { sbuf[qrow][pos] = key; mask |= (1u << bit); }
                    }
                }
            }
            __syncthreads();
            if (tid < MQT) {
                u32 n = cnt[tid];
                u32 m = n < SCAP ? n : SCAP;
                for (u32 e = 0; e < m; ++e) {
                    u64 key = sbuf[tid][e];
                    u64 last = ((u64)topkD[tid][KNN - 1] << 16) | topkI[tid][KNN - 1];
                    if (key < last) {
                        int p = KNN - 1;
                        while (p > 0) {
                            u64 prev = ((u64)topkD[tid][p - 1] << 16) | topkI[tid][p - 1];
                            if (prev > key) {
                                topkD[tid][p] = topkD[tid][p - 1];
                                topkI[tid][p] = topkI[tid][p - 1];
                                --p;
                            } else break;
                        }
                        topkD[tid][p] = (u32)(key >> 16);
                        topkI[tid][p] = (u16)(key & 0xFFFF);
                    }
                }
                u64 last = ((u64)topkD[tid][KNN - 1] << 16) | topkI[tid][KNN - 1];
                kth64[tid] = last < seedkey ? last : seedkey;
                if (n > SCAP) againF = 1;
                cnt[tid] = 0u;
            }
            __syncthreads();
            int go = againF;
            __syncthreads();
            if (tid == 0) againF = 0;
            if (!go) break;
            __syncthreads();
        }
    }

    __syncthreads();
    for (int i = tid; i < MQT * KNN; i += 512) {
        int q = i >> 5, k = i & 31;
        u64 key = ((u64)topkD[q][k] << 16) | topkI[q][k];
        cand[((size_t)(q0 + q) * NS + blockIdx.x) * KNN + k] = key;
    }
}

__launch_bounds__(256, 4)
__global__ void knn_part(const float* __restrict__ Xq, const float* __restrict__ Xt,
                         const float* __restrict__ q2, const float* __restrict__ t2,
                         u64* __restrict__ cand) {
    __shared__ float sQ[KK][QT];
    __shared__ float sT[KK][TT];
    __shared__ u64 topk[QT][KNN];
    __shared__ u64 buf[QT][FCAP];
    __shared__ u64 kth64[QT];
    __shared__ u32 cnt[QT];
    __shared__ int againF;

    const int tid = threadIdx.x;
    const int q0 = blockIdx.x * QT;
    const int t0 = blockIdx.y * SLICE;
    const int tq4 = (tid >> 5) * 4;
    const int tt4 = (tid & 31) * 4;
    const int pg = tid & 63;
    const int kg = tid >> 6;
    const int qp = tid & 31;
    const int kq = tid >> 5;

    for (int i = tid; i < QT * KNN; i += 256) ((u64*)topk)[i] = ~0ULL;
    if (tid < QT) { kth64[tid] = ~0ULL; cnt[tid] = 0u; }
    if (tid == 0) againF = 0;

    float qq[4];
    #pragma unroll
    for (int i = 0; i < 4; ++i) qq[i] = q2[q0 + tq4 + i];

    #pragma unroll 1
    for (int chunk = 0; chunk < SLICE / TT; ++chunk) {
        const int tbase = t0 + chunk * TT;
        float acc[4][8];
        #pragma unroll
        for (int i = 0; i < 4; ++i)
            #pragma unroll
            for (int j = 0; j < 8; ++j) acc[i][j] = 0.f;

        #pragma unroll 1
        for (int k0 = 0; k0 < DIM; k0 += KK) {
            __syncthreads();
            {
                const float* Tp = Xt + (size_t)(tbase + pg * 4) * DIM + k0 + kg * 4;
                float4 r0 = *(const float4*)(Tp);
                float4 r1 = *(const float4*)(Tp + DIM);
                float4 r2 = *(const float4*)(Tp + 2 * DIM);
                float4 r3 = *(const float4*)(Tp + 3 * DIM);
                *(float4*)&sT[kg * 4 + 0][pg * 4] = make_float4(r0.x, r1.x, r2.x, r3.x);
                *(float4*)&sT[kg * 4 + 1][pg * 4] = make_float4(r0.y, r1.y, r2.y, r3.y);
                *(float4*)&sT[kg * 4 + 2][pg * 4] = make_float4(r0.z, r1.z, r2.z, r3.z);
                *(float4*)&sT[kg * 4 + 3][pg * 4] = make_float4(r0.w, r1.w, r2.w, r3.w);
            }
            {
                float2 v = *(const float2*)(Xq + (size_t)(q0 + qp) * DIM + k0 + kq * 2);
                sQ[kq * 2 + 0][qp] = v.x;
                sQ[kq * 2 + 1][qp] = v.y;
            }
            __syncthreads();
            #pragma unroll
            for (int k = 0; k < KK; ++k) {
                float4 qv = *(const float4*)&sQ[k][tq4];
                float4 ta = *(const float4*)&sT[k][tt4];
                float4 tb = *(const float4*)&sT[k][128 + tt4];
                float qa[4] = {qv.x, qv.y, qv.z, qv.w};
                float tv[8] = {ta.x, ta.y, ta.z, ta.w, tb.x, tb.y, tb.z, tb.w};
                #pragma unroll
                for (int i = 0; i < 4; ++i)
                    #pragma unroll
                    for (int j = 0; j < 8; ++j)
                        acc[i][j] = fmaf(qa[i], tv[j], acc[i][j]);
            }
        }

        float t2v[8];
        #pragma unroll
        for (int j = 0; j < 4; ++j) {
            t2v[j]     = t2[tbase + tt4 + j];
            t2v[4 + j] = t2[tbase + 128 + tt4 + j];
        }
        #pragma unroll
        for (int i = 0; i < 4; ++i)
            #pragma unroll
            for (int j = 0; j < 8; ++j)
                acc[i][j] = fmaxf((qq[i] - 2.f * acc[i][j]) + t2v[j], 0.f);

        unsigned mask = 0;
        for (;;) {
            u64 kv[4];
            #pragma unroll
            for (int i = 0; i < 4; ++i) kv[i] = kth64[tq4 + i];
            #pragma unroll
            for (int i = 0; i < 4; ++i) {
                #pragma unroll
                for (int j = 0; j < 8; ++j) {
                    unsigned b = 1u << (i * 8 + j);
                    if (mask & b) continue;
                    int tloc = (j < 4) ? (tt4 + j) : (128 + tt4 + (j - 4));
                    u64 key = ((u64)__float_as_uint(acc[i][j]) << 16) |
                              (u64)(unsigned)(tbase + tloc);
                    if (key < kv[i]) {
                        unsigned pos = atomicAdd(&cnt[tq4 + i], 1u);
                        if (pos < FCAP) { buf[tq4 + i][pos] = key; mask |= b; }
                    }
                }
            }
            __syncthreads();
            if (tid < QT) {
                unsigned n = cnt[tid];
                unsigned m = n < FCAP ? n : FCAP;
                for (unsigned e = 0; e < m; ++e) {
                    u64 key = buf[tid][e];
                    if (key < topk[tid][KNN - 1]) {
                        int p = KNN - 1;
                        while (p > 0 && topk[tid][p - 1] > key) {
                            topk[tid][p] = topk[tid][p - 1];
                            --p;
                        }
                        topk[tid][p] = key;
                    }
                }
                kth64[tid] = topk[tid][KNN - 1];
                if (n > FCAP) againF = 1;
                cnt[tid] = 0u;
            }
            __syncthreads();
            int go = againF;
            __syncthreads();
            if (tid == 0) againF = 0;
            if (!go) break;
            __syncthreads();
        }
    }

    __syncthreads();
    for (int i = tid; i < QT * KNN; i += 256) {
        int q = i >> 5, k = i & 31;
        cand[((size_t)(q0 + q) * NS + blockIdx.y) * KNN + k] = topk[q][k];
    }
}

__global__ void knn_merge(const u64* __restrict__ cand,
                          const int* __restrict__ y_train, int* __restrict__ out) {
    __shared__ u64 keys[NS * KNN];
    __shared__ u64 top[KNN];
    __shared__ int counts[NC];
    int q = blockIdx.x;
    for (int i = threadIdx.x; i < NS * KNN; i += 64)
        keys[i] = cand[(size_t)q * NS * KNN + i];
    for (int i = threadIdx.x; i < NC; i += 64) counts[i] = 0;
    if (threadIdx.x < KNN) top[threadIdx.x] = ~0ULL;
    __syncthreads();

    if (threadIdx.x == 0) {
        for (int s = 0; s < NS; ++s) {
            for (int j = 0; j < KNN; ++j) {
                u64 key = keys[s * KNN + j];
                if (key >= top[KNN - 1]) break;
                int p = KNN - 1;
                while (p > 0 && top[p - 1] > key) { top[p] = top[p - 1]; --p; }
                top[p] = key;
            }
        }
        for (int k = 0; k < KNN; ++k) {
            int idx = (int)(top[k] & 0xFFFF);
            counts[y_train[idx]]++;
        }
        int bestc = counts[0], bestl = 0;
        for (int c = 1; c < NC; ++c)
            if (counts[c] > bestc) { bestc = counts[c]; bestl = c; }
        out[q] = bestl;
    }
}

extern "C" void kernel_launch(void* const* d_in, const int* in_sizes, int n_in,
                              void* d_out, int out_size, void* d_ws, size_t ws_size,
                              hipStream_t stream) {
    const float* Xq = (const float*)d_in[0];   // [2048, 512]
    const float* Xt = (const float*)d_in[1];   // [65536, 512]
    const int*   y  = (const int*)d_in[2];     // [65536]
    int* out = (int*)d_out;                    // [2048] int32

    float* t2 = (float*)d_ws;                                   // 256 KB
    float* q2 = t2 + NT;                                        // 8 KB
    u64* cand = (u64*)(q2 + NQ);                                // 16.8 MB (fallback paths)
    u32* seed = (u32*)(cand + (size_t)NQ * NS * KNN);           // 8 KB
    u16* Qh = (u16*)(seed + NQ);                                // 2 MB
    u16* Ql = Qh + (size_t)NQ * DIM;                            // 2 MB
    u16* Th = Ql + (size_t)NQ * DIM;                            // 64 MB
    u16* Tl = Th + (size_t)NT * DIM;                            // 64 MB
    u64* glist = (u64*)(Tl + (size_t)NT * DIM);                 // 64 MB (filter path)
    u32* gcnt  = (u32*)(glist + (size_t)NQ * GCAP);             // 8 KB
    float* Dpre = (float*)glist;                                // 16 MB, aliases glist (dead before gemm)

    const size_t need = (size_t)(NT + NQ) * 4
                      + (size_t)NQ * NS * KNN * 8
                      + (size_t)NQ * 4
                      + 2 * ((size_t)NQ * DIM + (size_t)NT * DIM) * 2;  // ~148.3 MB
    const bool use_mfma = ws_size >= need;
    const bool use_filter = ws_size >= need + (size_t)NQ * GCAP * 8 + (size_t)NQ * 4;  // +64 MB

    norm_kernel<<<NT / 4, 256, 0, stream>>>(Xt, t2, NT);
    norm_kernel<<<NQ / 4, 256, 0, stream>>>(Xq, q2, NQ);
    if (use_mfma && use_filter) {
        split_kernel<<<(NQ * DIM / 4 + 255) / 256, 256, 0, stream>>>(Xq, Qh, Ql, NQ * DIM / 4);
        split_kernel<<<(NT * DIM / 4 + 255) / 256, 256, 0, stream>>>(Xt, Th, Tl, NT * DIM / 4);
        knn_pre<<<dim3(NQ / PQT, NTPRE / PSLICE), 256, 0, stream>>>(Xq, Xt, q2, t2, Dpre);
        seed_topk<<<NQ, 64, 0, stream>>>(Dpre, seed);
        hipMemsetAsync(gcnt, 0, NQ * sizeof(u32), stream);
        gemm_filter<<<dim3(NQ / 128, NT / 128), 256, 0, stream>>>(
            Qh, Ql, Th, Tl, q2, t2, seed, gcnt, glist);
        knn_topk<<<NQ, 64, 0, stream>>>(glist, gcnt, y, out);
    } else if (use_mfma) {
        hipMemsetAsync(seed, 0xFF, NQ * sizeof(u32), stream);
        split_kernel<<<(NQ * DIM / 4 + 255) / 256, 256, 0, stream>>>(Xq, Qh, Ql, NQ * DIM / 4);
        split_kernel<<<(NT * DIM / 4 + 255) / 256, 256, 0, stream>>>(Xt, Th, Tl, NT * DIM / 4);
        knn_prepass<<<dim3(NQ / PQT, NTPRE / PSLICE), 256, 0, stream>>>(Xq, Xt, q2, t2, seed);
        knn_mfma<<<dim3(NT / MSLICE, NQ / MQT), 512, 0, stream>>>(Qh, Ql, Th, Tl, q2, t2, seed, cand);
        knn_merge<<<NQ, 64, 0, stream>>>(cand, y, out);
    } else {
        knn_part<<<dim3(NQ / QT, NS), 256, 0, stream>>>(Xq, Xt, q2, t2, cand);
        knn_merge<<<NQ, 64, 0, stream>>>(cand, y, out);
    }
}

// Round 8
// 1191.163 us; speedup vs baseline: 3.0500x; 1.0604x over previous
//
#include <hip/hip_runtime.h>
#include <hip/hip_bf16.h>
#include <stdint.h>

typedef unsigned long long u64;
typedef unsigned int u32;
typedef unsigned short u16;
typedef __attribute__((ext_vector_type(8))) short short8;
typedef __attribute__((ext_vector_type(16))) float float16;

#define NQ 2048
#define NT 65536
#define DIM 512
#define KNN 32
#define NC 100
#define NS 32               // slices (fallback paths), cand[q][slice][k]

// ---- fallback (R2) params ----
#define QT 32
#define SLICE (NT / NS)     // 2048
#define TT 256
#define KK 16
#define FCAP 32

// ---- prepass params (fp32, trains 0..2047 subsample) ----
#define PQT 32
#define PTT 256
#define PSLICE 512
#define NTPRE 2048

// ---- fused-mfma fallback params (R4, proven) ----
#define MQT 128
#define MTT 128
#define MBK 32
#define MSLICE 2048
#define SCAP 16
#define NTILES 256

// ---- filter-path params (R6, proven) ----
#define GCAP 4096           // per-query candidate capacity; exact-2048 seed admits ~1024±180 (17 sigma)

// ---------------- row-norm kernel ----------------
__global__ void norm_kernel(const float* __restrict__ X, float* __restrict__ out, int nrows) {
    int row = blockIdx.x * 4 + (threadIdx.x >> 6);
    int lane = threadIdx.x & 63;
    if (row >= nrows) return;
    const float4* p = (const float4*)(X + (size_t)row * DIM);
    float4 a = p[lane];
    float4 b = p[lane + 64];
    float s = a.x*a.x + a.y*a.y + a.z*a.z + a.w*a.w
            + b.x*b.x + b.y*b.y + b.z*b.z + b.w*b.w;
    #pragma unroll
    for (int off = 32; off > 0; off >>= 1) s += __shfl_down(s, off, 64);
    if (lane == 0) out[row] = s;
}

// ---------------- bf16 hi/lo split ----------------
__global__ void split_kernel(const float* __restrict__ X, u16* __restrict__ H,
                             u16* __restrict__ L, int n4) {
    int i = blockIdx.x * 256 + threadIdx.x;
    if (i >= n4) return;
    float4 v = ((const float4*)X)[i];
    float f[4] = {v.x, v.y, v.z, v.w};
    u16 hh[4], ll[4];
    #pragma unroll
    for (int j = 0; j < 4; ++j) {
        union { __hip_bfloat16 b; u16 u; } cv;
        cv.b = __float2bfloat16(f[j]);
        hh[j] = cv.u;
        float hf = __bfloat162float(cv.b);
        cv.b = __float2bfloat16(f[j] - hf);
        ll[j] = cv.u;
    }
    ((ushort4*)H)[i] = make_ushort4(hh[0], hh[1], hh[2], hh[3]);
    ((ushort4*)L)[i] = make_ushort4(ll[0], ll[1], ll[2], ll[3]);
}

// ---------------- knn_pre: fp32 distances for trains 0..2047, written to Dpre --------------
// grid: (NQ/PQT=64, NTPRE/PSLICE=4), 256 thr. Pure compute+store; no selection protocol.
__launch_bounds__(256, 2)
__global__ void knn_pre(const float* __restrict__ Xq, const float* __restrict__ Xt,
                        const float* __restrict__ q2, const float* __restrict__ t2,
                        float* __restrict__ Dpre) {
    __shared__ float sQ[KK][PQT];
    __shared__ float sT[KK][PTT];

    const int tid = threadIdx.x;
    const int q0 = blockIdx.x * PQT;
    const int t0p = blockIdx.y * PSLICE;
    const int tq4 = (tid >> 5) * 4;
    const int tt4 = (tid & 31) * 4;
    const int pg = tid & 63;
    const int kg = tid >> 6;
    const int qp = tid & 31;
    const int kq = tid >> 5;

    float qq[4];
    #pragma unroll
    for (int i = 0; i < 4; ++i) qq[i] = q2[q0 + tq4 + i];

    #pragma unroll 1
    for (int chunk = 0; chunk < PSLICE / PTT; ++chunk) {
        const int tbase = t0p + chunk * PTT;
        float acc[4][8];
        #pragma unroll
        for (int i = 0; i < 4; ++i)
            #pragma unroll
            for (int j = 0; j < 8; ++j) acc[i][j] = 0.f;

        #pragma unroll 1
        for (int k0 = 0; k0 < DIM; k0 += KK) {
            __syncthreads();   // protects sQ/sT reuse
            {
                const float* Tp = Xt + (size_t)(tbase + pg * 4) * DIM + k0 + kg * 4;
                float4 r0 = *(const float4*)(Tp);
                float4 r1 = *(const float4*)(Tp + DIM);
                float4 r2 = *(const float4*)(Tp + 2 * DIM);
                float4 r3 = *(const float4*)(Tp + 3 * DIM);
                *(float4*)&sT[kg * 4 + 0][pg * 4] = make_float4(r0.x, r1.x, r2.x, r3.x);
                *(float4*)&sT[kg * 4 + 1][pg * 4] = make_float4(r0.y, r1.y, r2.y, r3.y);
                *(float4*)&sT[kg * 4 + 2][pg * 4] = make_float4(r0.z, r1.z, r2.z, r3.z);
                *(float4*)&sT[kg * 4 + 3][pg * 4] = make_float4(r0.w, r1.w, r2.w, r3.w);
            }
            {
                float2 v = *(const float2*)(Xq + (size_t)(q0 + qp) * DIM + k0 + kq * 2);
                sQ[kq * 2 + 0][qp] = v.x;
                sQ[kq * 2 + 1][qp] = v.y;
            }
            __syncthreads();
            #pragma unroll
            for (int k = 0; k < KK; ++k) {
                float4 qv = *(const float4*)&sQ[k][tq4];
                float4 ta = *(const float4*)&sT[k][tt4];
                float4 tb = *(const float4*)&sT[k][128 + tt4];
                float qa[4] = {qv.x, qv.y, qv.z, qv.w};
                float tv[8] = {ta.x, ta.y, ta.z, ta.w, tb.x, tb.y, tb.z, tb.w};
                #pragma unroll
                for (int i = 0; i < 4; ++i)
                    #pragma unroll
                    for (int j = 0; j < 8; ++j)
                        acc[i][j] = fmaf(qa[i], tv[j], acc[i][j]);
            }
        }

        float t2v[8];
        #pragma unroll
        for (int j = 0; j < 4; ++j) {
            t2v[j]     = t2[tbase + tt4 + j];
            t2v[4 + j] = t2[tbase + 128 + tt4 + j];
        }
        #pragma unroll
        for (int i = 0; i < 4; ++i) {
            float4 lo, hi;
            lo.x = fmaxf(qq[i] - 2.f * acc[i][0] + t2v[0], 0.f);
            lo.y = fmaxf(qq[i] - 2.f * acc[i][1] + t2v[1], 0.f);
            lo.z = fmaxf(qq[i] - 2.f * acc[i][2] + t2v[2], 0.f);
            lo.w = fmaxf(qq[i] - 2.f * acc[i][3] + t2v[3], 0.f);
            hi.x = fmaxf(qq[i] - 2.f * acc[i][4] + t2v[4], 0.f);
            hi.y = fmaxf(qq[i] - 2.f * acc[i][5] + t2v[5], 0.f);
            hi.z = fmaxf(qq[i] - 2.f * acc[i][6] + t2v[6], 0.f);
            hi.w = fmaxf(qq[i] - 2.f * acc[i][7] + t2v[7], 0.f);
            *(float4*)&Dpre[(size_t)(q0 + tq4 + i) * NTPRE + tbase + tt4] = lo;
            *(float4*)&Dpre[(size_t)(q0 + tq4 + i) * NTPRE + tbase + 128 + tt4] = hi;
        }
    }
}

// ---------------- seed_topk: exact 32nd-smallest of Dpre row -> seed[q] -------------------
__launch_bounds__(64)
__global__ void seed_topk(const float* __restrict__ Dpre, u32* __restrict__ seed) {
    __shared__ u64 ll[64][KNN + 1];   // pad: stride 33 u64 -> 2-way banks only
    const int q = blockIdx.x;
    const int lane = threadIdx.x;
    #pragma unroll
    for (int j = 0; j <= KNN; ++j) ll[lane][j] = ~0ULL;
    const float* src = Dpre + (size_t)q * NTPRE;
    u64 kth = ~0ULL;
    for (int i = lane; i < NTPRE; i += 64) {
        u64 key = (u64)__float_as_uint(src[i]);
        if (key < kth) {
            int p = KNN - 1;
            while (p > 0 && ll[lane][p - 1] > key) { ll[lane][p] = ll[lane][p - 1]; --p; }
            ll[lane][p] = key;
            kth = ll[lane][KNN - 1];
        }
    }
    __syncthreads();
    int ptr = 0;
    u64 cur = ll[lane][0];
    u64 m = 0;
    for (int it = 0; it < KNN; ++it) {
        m = cur;
        #pragma unroll
        for (int off = 32; off > 0; off >>= 1) {
            u64 o = __shfl_xor(m, off, 64);
            m = (o < m) ? o : m;
        }
        u64 got = __ballot(cur == m);
        int w = __ffsll(got) - 1;
        if (lane == w) { ++ptr; cur = (ptr < KNN) ? ll[lane][ptr] : ~0ULL; }
    }
    if (lane == 0) seed[q] = (u32)m;   // 32nd smallest dist bits (exact over 2048 subsample)
}

// ---------------- async global->LDS 16B ----------------
__device__ __forceinline__ void gld16(const void* g, void* l) {
    __builtin_amdgcn_global_load_lds(
        (const __attribute__((address_space(1))) u32*)g,
        (__attribute__((address_space(3))) u32*)l, 16, 0, 0);
}

// ---------------- gemm_filter: pipelined 128x128 GEMM + seed-filter push epilogue ---------
// R8 changes (attacking the measured ~3300 cyc/window drain-stall):
//  (1) XCD colocation: wg = (bid&7)*1024 + bid>>3 -> each XCD owns 64 consecutive y-tiles
//      with all 16 q-tiles. Every 256 KB T-tile fills exactly ONE L2, once. (bijective: 8192%8==0)
//  (2) Double-buffer, issue-before-compute: stage(T+1) -> compute(T) [24 MFMA + 16 ds_read
//      ~500-700 cyc covers L2-hit latency] -> vmcnt(0) residual -> s_barrier. The old shape
//      {barrier; issue; barrier(vmcnt0)} gave loads ZERO compute cover.
// LDS 2x32KB + 1.6KB = 66 KB -> 2 blocks/CU.
__launch_bounds__(256, 2)
__global__ void gemm_filter(const u16* __restrict__ Qh, const u16* __restrict__ Ql,
                            const u16* __restrict__ Th, const u16* __restrict__ Tl,
                            const float* __restrict__ q2, const float* __restrict__ t2,
                            const u32* __restrict__ seed,
                            u32* __restrict__ gcnt, u64* __restrict__ glist) {
    __shared__ __align__(16) u16 tiles[2][4][4096];   // [buf][plane Ah,Al,Bh,Bl][128*32]
    __shared__ float sQ2L[128];
    __shared__ float sT2L[128];
    __shared__ u32 sSeed[128];

    const int tid = threadIdx.x;
    const int lane = tid & 63;
    const int wid = tid >> 6;             // 0..3
    const int bid = blockIdx.x + (int)(gridDim.x * blockIdx.y);   // x fastest (gridDim.x=16)
    const int wg  = ((bid & 7) << 10) + (bid >> 3);               // XCD-colocating remap
    const int q0g = (wg & 15) * 128;      // query base
    const int tb  = (wg >> 4) * 128;      // train base (64 consecutive y per XCD)
    const int m_off = (wid >> 1) * 64;
    const int n_off = (wid & 1) * 64;
    const int swz = ((lane >> 1) & 3) << 3;
    const int l4r = lane >> 2;
    const int l4c = (((lane & 3) ^ ((lane >> 3) & 3)) * 8);

    if (tid < 128) {
        sQ2L[tid] = q2[q0g + tid];
        sT2L[tid] = t2[tb + tid];
        sSeed[tid] = seed[q0g + tid] + 256u;   // admission threshold (+ulp margin)
    }

    float16 acc[2][2];
    acc[0][0] = (float16)(0.0f); acc[0][1] = (float16)(0.0f);
    acc[1][0] = (float16)(0.0f); acc[1][1] = (float16)(0.0f);

    // stage one tile (8 gld16 per wave): planes u=0..3, row-groups j=0..1
    #define STAGE_TILE(BUF, K0)                                                        \
        do {                                                                           \
            _Pragma("unroll")                                                          \
            for (int u = 0; u < 4; ++u) {                                              \
                const u16* P = (u == 0) ? Qh : (u == 1) ? Ql : (u == 2) ? Th : Tl;     \
                const int rb = (u < 2) ? q0g : tb;                                     \
                _Pragma("unroll")                                                      \
                for (int j = 0; j < 2; ++j) {                                          \
                    const int rg = j * 64 + wid * 16;                                  \
                    gld16(P + (size_t)(rb + rg + l4r) * DIM + (K0) + l4c,              \
                          (u16*)tiles[BUF][u] + rg * 32);                              \
                }                                                                      \
            }                                                                          \
        } while (0)

    STAGE_TILE(0, 0);
    __syncthreads();   // prologue drain: tile 0 ready, sQ2L/sT2L/sSeed visible

    int cur = 0;
    #pragma unroll 1
    for (int t = 0; t < DIM / MBK; ++t) {
        if (t + 1 < DIM / MBK) STAGE_TILE(cur ^ 1, (t + 1) * MBK);   // issue early

        const u16* pA0 = tiles[cur][0];
        const u16* pA1 = tiles[cur][1];
        const u16* pB0 = tiles[cur][2];
        const u16* pB1 = tiles[cur][3];
        #pragma unroll
        for (int s = 0; s < 2; ++s) {
            const int kb = (s * 16 + (lane >> 5) * 8) ^ swz;
            short8 ah[2], al[2], bh[2], bl[2];
            #pragma unroll
            for (int mi = 0; mi < 2; ++mi) {
                int row = m_off + mi * 32 + (lane & 31);
                ah[mi] = *(const short8*)(const void*)&pA0[row * 32 + kb];
                al[mi] = *(const short8*)(const void*)&pA1[row * 32 + kb];
            }
            #pragma unroll
            for (int nj = 0; nj < 2; ++nj) {
                int row = n_off + nj * 32 + (lane & 31);
                bh[nj] = *(const short8*)(const void*)&pB0[row * 32 + kb];
                bl[nj] = *(const short8*)(const void*)&pB1[row * 32 + kb];
            }
            #pragma unroll
            for (int mi = 0; mi < 2; ++mi)
                #pragma unroll
                for (int nj = 0; nj < 2; ++nj) {
                    acc[mi][nj] = __builtin_amdgcn_mfma_f32_32x32x16_bf16(ah[mi], bh[nj], acc[mi][nj], 0, 0, 0);
                    acc[mi][nj] = __builtin_amdgcn_mfma_f32_32x32x16_bf16(ah[mi], bl[nj], acc[mi][nj], 0, 0, 0);
                    acc[mi][nj] = __builtin_amdgcn_mfma_f32_32x32x16_bf16(al[mi], bh[nj], acc[mi][nj], 0, 0, 0);
                }
        }
        // residual wait only: next tile's loads had the whole compute phase in flight
        asm volatile("s_waitcnt vmcnt(0)" ::: "memory");
        __builtin_amdgcn_s_barrier();
        __builtin_amdgcn_sched_barrier(0);
        cur ^= 1;
    }
    #undef STAGE_TILE

    // epilogue: rare filtered push (frag map: col=lane&31, row=(r&3)+8*(r>>2)+4*(lane>>5))
    #pragma unroll
    for (int mi = 0; mi < 2; ++mi)
        #pragma unroll
        for (int nj = 0; nj < 2; ++nj) {
            const int tcol_l = n_off + nj * 32 + (lane & 31);
            const float t2v = sT2L[tcol_l];
            #pragma unroll
            for (int r = 0; r < 16; ++r) {
                const int qrow_l = m_off + mi * 32 + (r & 3) + 8 * (r >> 2) + 4 * (lane >> 5);
                float d = fmaxf(sQ2L[qrow_l] - 2.0f * acc[mi][nj][r] + t2v, 0.0f);
                if (__float_as_uint(d) <= sSeed[qrow_l]) {
                    const int q = q0g + qrow_l;
                    u32 pos = atomicAdd(&gcnt[q], 1u);
                    if (pos < GCAP)
                        glist[(size_t)q * GCAP + pos] =
                            ((u64)__float_as_uint(d) << 16) | (u64)(u32)(tb + tcol_l);
                }
            }
        }
}

// ---------------- knn_topk: exact top-32 over candidate list + vote -> out ----------------
__launch_bounds__(64)
__global__ void knn_topk(const u64* __restrict__ glist, const u32* __restrict__ gcnt,
                         const int* __restrict__ y_train, int* __restrict__ out) {
    __shared__ u64 ll[64][KNN + 1];
    __shared__ u64 fin[KNN];
    __shared__ int counts[NC];
    const int q = blockIdx.x;
    const int lane = threadIdx.x;
    #pragma unroll
    for (int j = 0; j <= KNN; ++j) ll[lane][j] = ~0ULL;
    for (int i = lane; i < NC; i += 64) counts[i] = 0;
    u32 n = gcnt[q]; if (n > GCAP) n = GCAP;
    const u64* src = glist + (size_t)q * GCAP;
    u64 kth = ~0ULL;
    for (u32 i = lane; i < n; i += 64) {
        u64 key = src[i];
        if (key < kth) {
            int p = KNN - 1;
            while (p > 0 && ll[lane][p - 1] > key) { ll[lane][p] = ll[lane][p - 1]; --p; }
            ll[lane][p] = key;
            kth = ll[lane][KNN - 1];
        }
    }
    __syncthreads();
    int ptr = 0;
    u64 cur = ll[lane][0];
    for (int it = 0; it < KNN; ++it) {
        u64 m = cur;
        #pragma unroll
        for (int off = 32; off > 0; off >>= 1) {
            u64 o = __shfl_xor(m, off, 64);
            m = (o < m) ? o : m;
        }
        u64 got = __ballot(cur == m);
        int w = __ffsll(got) - 1;
        if (lane == 0) fin[it] = m;
        if (lane == w) { ++ptr; cur = (ptr < KNN) ? ll[lane][ptr] : ~0ULL; }
    }
    __syncthreads();
    if (lane < KNN) {
        int idx = (int)(fin[lane] & 0xFFFF);
        atomicAdd(&counts[y_train[idx]], 1);
    }
    __syncthreads();
    if (lane == 0) {
        int bestc = counts[0], bestl = 0;
        for (int c = 1; c < NC; ++c)
            if (counts[c] > bestc) { bestc = counts[c]; bestl = c; }
        out[q] = bestl;
    }
}

// ================= fallback machinery (R4 fused path + fp32 path), proven =================

__launch_bounds__(256, 2)
__global__ void knn_prepass(const float* __restrict__ Xq, const float* __restrict__ Xt,
                            const float* __restrict__ q2, const float* __restrict__ t2,
                            u32* __restrict__ seed) {
    __shared__ float sQ[KK][PQT];
    __shared__ float sT[KK][PTT];
    __shared__ float sD[PQT][PTT + 1];
    __shared__ u32 topk[PQT][KNN + 1];

    const int tid = threadIdx.x;
    const int q0 = blockIdx.x * PQT;
    const int t0p = blockIdx.y * PSLICE;
    const int tq4 = (tid >> 5) * 4;
    const int tt4 = (tid & 31) * 4;
    const int pg = tid & 63;
    const int kg = tid >> 6;
    const int qp = tid & 31;
    const int kq = tid >> 5;

    for (int i = tid; i < PQT * (KNN + 1); i += 256) ((u32*)topk)[i] = 0xFFFFFFFFu;
    u32 kth = 0xFFFFFFFFu;

    float qq[4];
    #pragma unroll
    for (int i = 0; i < 4; ++i) qq[i] = q2[q0 + tq4 + i];

    #pragma unroll 1
    for (int chunk = 0; chunk < PSLICE / PTT; ++chunk) {
        const int tbase = t0p + chunk * PTT;
        float acc[4][8];
        #pragma unroll
        for (int i = 0; i < 4; ++i)
            #pragma unroll
            for (int j = 0; j < 8; ++j) acc[i][j] = 0.f;

        #pragma unroll 1
        for (int k0 = 0; k0 < DIM; k0 += KK) {
            __syncthreads();
            {
                const float* Tp = Xt + (size_t)(tbase + pg * 4) * DIM + k0 + kg * 4;
                float4 r0 = *(const float4*)(Tp);
                float4 r1 = *(const float4*)(Tp + DIM);
                float4 r2 = *(const float4*)(Tp + 2 * DIM);
                float4 r3 = *(const float4*)(Tp + 3 * DIM);
                *(float4*)&sT[kg * 4 + 0][pg * 4] = make_float4(r0.x, r1.x, r2.x, r3.x);
                *(float4*)&sT[kg * 4 + 1][pg * 4] = make_float4(r0.y, r1.y, r2.y, r3.y);
                *(float4*)&sT[kg * 4 + 2][pg * 4] = make_float4(r0.z, r1.z, r2.z, r3.z);
                *(float4*)&sT[kg * 4 + 3][pg * 4] = make_float4(r0.w, r1.w, r2.w, r3.w);
            }
            {
                float2 v = *(const float2*)(Xq + (size_t)(q0 + qp) * DIM + k0 + kq * 2);
                sQ[kq * 2 + 0][qp] = v.x;
                sQ[kq * 2 + 1][qp] = v.y;
            }
            __syncthreads();
            #pragma unroll
            for (int k = 0; k < KK; ++k) {
                float4 qv = *(const float4*)&sQ[k][tq4];
                float4 ta = *(const float4*)&sT[k][tt4];
                float4 tb = *(const float4*)&sT[k][128 + tt4];
                float qa[4] = {qv.x, qv.y, qv.z, qv.w};
                float tv[8] = {ta.x, ta.y, ta.z, ta.w, tb.x, tb.y, tb.z, tb.w};
                #pragma unroll
                for (int i = 0; i < 4; ++i)
                    #pragma unroll
                    for (int j = 0; j < 8; ++j)
                        acc[i][j] = fmaf(qa[i], tv[j], acc[i][j]);
            }
        }

        #pragma unroll
        for (int i = 0; i < 4; ++i)
            #pragma unroll
            for (int j = 0; j < 8; ++j) {
                int t = (j < 4) ? (tt4 + j) : (128 + tt4 + (j - 4));
                sD[tq4 + i][t] = fmaxf((qq[i] - 2.f * acc[i][j]) + t2[tbase + t], 0.f);
            }
        __syncthreads();

        if (tid < PQT) {
            for (int t = 0; t < PTT; ++t) {
                u32 d = __float_as_uint(sD[tid][t]);
                if (d < kth) {
                    int p = KNN - 1;
                    while (p > 0 && topk[tid][p - 1] > d) {
                        topk[tid][p] = topk[tid][p - 1];
                        --p;
                    }
                    topk[tid][p] = d;
                    kth = topk[tid][KNN - 1];
                }
            }
        }
    }
    if (tid < PQT) atomicMin(&seed[q0 + tid], kth);
}

__device__ __forceinline__ void stage_tile(const u16* __restrict__ Qh, const u16* __restrict__ Ql,
                                           const u16* __restrict__ Th, const u16* __restrict__ Tl,
                                           u16* base, int q0, int tb, int k0, int wid, int lane) {
    const int l4r = lane >> 2;
    const int l4c = (((lane & 3) ^ ((lane >> 3) & 3)) * 8);
    #pragma unroll
    for (int u = 0; u < 4; ++u) {
        const u16* P = (u == 0) ? Qh : (u == 1) ? Ql : (u == 2) ? Th : Tl;
        const int r0 = (u < 2) ? q0 : tb;
        const u16* g = P + (size_t)(r0 + wid * 16 + l4r) * DIM + k0 + l4c;
        gld16(g, base + u * 4096 + wid * 512);
    }
}

__launch_bounds__(512, 1)
__global__ void knn_mfma(const u16* __restrict__ Qh, const u16* __restrict__ Ql,
                         const u16* __restrict__ Th, const u16* __restrict__ Tl,
                         const float* __restrict__ q2, const float* __restrict__ t2,
                         const u32* __restrict__ seed, u64* __restrict__ cand) {
    __shared__ __align__(16) u16 tiles[3][16384];
    __shared__ u32 topkD[MQT][KNN + 1];
    __shared__ u16 topkI[MQT][KNN + 1];
    __shared__ u64 sbuf[MQT][SCAP];
    __shared__ u64 kth64[MQT];
    __shared__ u32 cnt[MQT];
    __shared__ float sQ2[MQT];
    __shared__ float sT2[MTT];
    __shared__ int againF;

    const int tid = threadIdx.x;
    const int lane = tid & 63;
    const int wid = tid >> 6;
    const int q0 = blockIdx.y * MQT;
    const int s0 = blockIdx.x * MSLICE;
    const int m_off = (wid >> 2) * 64;
    const int n_off = (wid & 3) * 32;
    const int swz = ((lane >> 1) & 3) << 3;

    for (int i = tid; i < MQT * (KNN + 1); i += 512) {
        ((u32*)topkD)[i] = 0xFFFFFFFFu;
        ((u16*)topkI)[i] = 0xFFFFu;
    }
    u64 seedkey = ~0ULL;
    if (tid < MQT) {
        seedkey = ((u64)seed[q0 + tid] + 1) << 16;
        kth64[tid] = seedkey;
        cnt[tid] = 0u;
        sQ2[tid] = q2[q0 + tid];
    }
    if (tid == 0) againF = 0;

    stage_tile(Qh, Ql, Th, Tl, tiles[0], q0, s0, 0, wid, lane);
    stage_tile(Qh, Ql, Th, Tl, tiles[1], q0, s0, MBK, wid, lane);
    __syncthreads();

    int cb = 0;
    #pragma unroll 1
    for (int chunk = 0; chunk < MSLICE / MTT; ++chunk) {
        const int tb = s0 + chunk * MTT;
        float16 acc[2];
        acc[0] = (float16)(0.0f);
        acc[1] = (float16)(0.0f);

        #pragma unroll 1
        for (int t = 0; t < DIM / MBK; ++t) {
            const int Tn = chunk * 16 + t + 2;
            const bool pf = (Tn < NTILES);
            if (pf) {
                int bn = cb + 2; if (bn >= 3) bn -= 3;
                stage_tile(Qh, Ql, Th, Tl, tiles[bn], q0,
                           s0 + (Tn >> 4) * MTT, (Tn & 15) * MBK, wid, lane);
            }
            const u16* sAh = tiles[cb];
            const u16* sAl = sAh + 4096;
            const u16* sBh = sAh + 8192;
            const u16* sBl = sAh + 12288;
            #pragma unroll
            for (int s = 0; s < 2; ++s) {
                const int kb = (s * 16 + (lane >> 5) * 8) ^ swz;
                short8 ah[2], al[2];
                #pragma unroll
                for (int mi = 0; mi < 2; ++mi) {
                    int row = m_off + mi * 32 + (lane & 31);
                    ah[mi] = *(const short8*)(const void*)&sAh[row * MBK + kb];
                    al[mi] = *(const short8*)(const void*)&sAl[row * MBK + kb];
                }
                int brow = n_off + (lane & 31);
                short8 bh = *(const short8*)(const void*)&sBh[brow * MBK + kb];
                short8 bl = *(const short8*)(const void*)&sBl[brow * MBK + kb];
                #pragma unroll
                for (int mi = 0; mi < 2; ++mi) {
                    acc[mi] = __builtin_amdgcn_mfma_f32_32x32x16_bf16(ah[mi], bh, acc[mi], 0, 0, 0);
                    acc[mi] = __builtin_amdgcn_mfma_f32_32x32x16_bf16(ah[mi], bl, acc[mi], 0, 0, 0);
                    acc[mi] = __builtin_amdgcn_mfma_f32_32x32x16_bf16(al[mi], bh, acc[mi], 0, 0, 0);
                }
            }
            if (pf) asm volatile("s_waitcnt vmcnt(4)" ::: "memory");
            else    asm volatile("s_waitcnt vmcnt(0)" ::: "memory");
            __builtin_amdgcn_s_barrier();
            __builtin_amdgcn_sched_barrier(0);
            ++cb; if (cb >= 3) cb = 0;
        }

        if (tid < MTT) sT2[tid] = t2[tb + tid];
        __syncthreads();
        const float t2r = sT2[n_off + (lane & 31)];
        const int tcol = n_off + (lane & 31);

        u32 mask = 0;
        for (;;) {
            #pragma unroll
            for (int mi = 0; mi < 2; ++mi) {
                #pragma unroll
                for (int r = 0; r < 16; ++r) {
                    const int bit = mi * 16 + r;
                    if ((mask >> bit) & 1) continue;
                    const int qrow = m_off + mi * 32 + (r & 3) + 8 * (r >> 2) + 4 * (lane >> 5);
                    float d = fmaxf(sQ2[qrow] - 2.0f * acc[mi][r] + t2r, 0.0f);
                    u64 key = ((u64)__float_as_uint(d) << 16) | (u64)(u32)(tb + tcol);
                    if (key < kth64[qrow]) {
                        u32 pos = atomicAdd(&cnt[qrow], 1u);
                        if (pos < SCAP) { sbuf[qrow][pos] = key; mask |= (1u << bit); }
                    }
                }
            }
            __syncthreads();
            if (tid < MQT) {
                u32 n = cnt[tid];
                u32 m = n < SCAP ? n : SCAP;
                for (u32 e = 0; e < m; ++e) {
                    u64 key = sbuf[tid][e];
                    u64 last = ((u64)topkD[tid][KNN - 1] << 16) | topkI[tid][KNN - 1];
                    if (key < last) {
                        int p = KNN - 1;
                        while (p > 0) {
                            u64 prev = ((u64)topkD[tid][p - 1] << 16) | topkI[tid][p - 1];
                            if (prev > key) {
                                topkD[tid][p] = topkD[tid][p - 1];
                                topkI[tid][p] = topkI[tid][p - 1];
                                --p;
                            } else break;
                        }
                        topkD[tid][p] = (u32)(key >> 16);
                        topkI[tid][p] = (u16)(key & 0xFFFF);
                    }
                }
                u64 last = ((u64)topkD[tid][KNN - 1] << 16) | topkI[tid][KNN - 1];
                kth64[tid] = last < seedkey ? last : seedkey;
                if (n > SCAP) againF = 1;
                cnt[tid] = 0u;
            }
            __syncthreads();
            int go = againF;
            __syncthreads();
            if (tid == 0) againF = 0;
            if (!go) break;
            __syncthreads();
        }
    }

    __syncthreads();
    for (int i = tid; i < MQT * KNN; i += 512) {
        int q = i >> 5, k = i & 31;
        u64 key = ((u64)topkD[q][k] << 16) | topkI[q][k];
        cand[((size_t)(q0 + q) * NS + blockIdx.x) * KNN + k] = key;
    }
}

__launch_bounds__(256, 4)
__global__ void knn_part(const float* __restrict__ Xq, const float* __restrict__ Xt,
                         const float* __restrict__ q2, const float* __restrict__ t2,
                         u64* __restrict__ cand) {
    __shared__ float sQ[KK][QT];
    __shared__ float sT[KK][TT];
    __shared__ u64 topk[QT][KNN];
    __shared__ u64 buf[QT][FCAP];
    __shared__ u64 kth64[QT];
    __shared__ u32 cnt[QT];
    __shared__ int againF;

    const int tid = threadIdx.x;
    const int q0 = blockIdx.x * QT;
    const int t0 = blockIdx.y * SLICE;
    const int tq4 = (tid >> 5) * 4;
    const int tt4 = (tid & 31) * 4;
    const int pg = tid & 63;
    const int kg = tid >> 6;
    const int qp = tid & 31;
    const int kq = tid >> 5;

    for (int i = tid; i < QT * KNN; i += 256) ((u64*)topk)[i] = ~0ULL;
    if (tid < QT) { kth64[tid] = ~0ULL; cnt[tid] = 0u; }
    if (tid == 0) againF = 0;

    float qq[4];
    #pragma unroll
    for (int i = 0; i < 4; ++i) qq[i] = q2[q0 + tq4 + i];

    #pragma unroll 1
    for (int chunk = 0; chunk < SLICE / TT; ++chunk) {
        const int tbase = t0 + chunk * TT;
        float acc[4][8];
        #pragma unroll
        for (int i = 0; i < 4; ++i)
            #pragma unroll
            for (int j = 0; j < 8; ++j) acc[i][j] = 0.f;

        #pragma unroll 1
        for (int k0 = 0; k0 < DIM; k0 += KK) {
            __syncthreads();
            {
                const float* Tp = Xt + (size_t)(tbase + pg * 4) * DIM + k0 + kg * 4;
                float4 r0 = *(const float4*)(Tp);
                float4 r1 = *(const float4*)(Tp + DIM);
                float4 r2 = *(const float4*)(Tp + 2 * DIM);
                float4 r3 = *(const float4*)(Tp + 3 * DIM);
                *(float4*)&sT[kg * 4 + 0][pg * 4] = make_float4(r0.x, r1.x, r2.x, r3.x);
                *(float4*)&sT[kg * 4 + 1][pg * 4] = make_float4(r0.y, r1.y, r2.y, r3.y);
                *(float4*)&sT[kg * 4 + 2][pg * 4] = make_float4(r0.z, r1.z, r2.z, r3.z);
                *(float4*)&sT[kg * 4 + 3][pg * 4] = make_float4(r0.w, r1.w, r2.w, r3.w);
            }
            {
                float2 v = *(const float2*)(Xq + (size_t)(q0 + qp) * DIM + k0 + kq * 2);
                sQ[kq * 2 + 0][qp] = v.x;
                sQ[kq * 2 + 1][qp] = v.y;
            }
            __syncthreads();
            #pragma unroll
            for (int k = 0; k < KK; ++k) {
                float4 qv = *(const float4*)&sQ[k][tq4];
                float4 ta = *(const float4*)&sT[k][tt4];
                float4 tb = *(const float4*)&sT[k][128 + tt4];
                float qa[4] = {qv.x, qv.y, qv.z, qv.w};
                float tv[8] = {ta.x, ta.y, ta.z, ta.w, tb.x, tb.y, tb.z, tb.w};
                #pragma unroll
                for (int i = 0; i < 4; ++i)
                    #pragma unroll
                    for (int j = 0; j < 8; ++j)
                        acc[i][j] = fmaf(qa[i], tv[j], acc[i][j]);
            }
        }

        float t2v[8];
        #pragma unroll
        for (int j = 0; j < 4; ++j) {
            t2v[j]     = t2[tbase + tt4 + j];
            t2v[4 + j] = t2[tbase + 128 + tt4 + j];
        }
        #pragma unroll
        for (int i = 0; i < 4; ++i)
            #pragma unroll
            for (int j = 0; j < 8; ++j)
                acc[i][j] = fmaxf((qq[i] - 2.f * acc[i][j]) + t2v[j], 0.f);

        unsigned mask = 0;
        for (;;) {
            u64 kv[4];
            #pragma unroll
            for (int i = 0; i < 4; ++i) kv[i] = kth64[tq4 + i];
            #pragma unroll
            for (int i = 0; i < 4; ++i) {
                #pragma unroll
                for (int j = 0; j < 8; ++j) {
                    unsigned b = 1u << (i * 8 + j);
                    if (mask & b) continue;
                    int tloc = (j < 4) ? (tt4 + j) : (128 + tt4 + (j - 4));
                    u64 key = ((u64)__float_as_uint(acc[i][j]) << 16) |
                              (u64)(unsigned)(tbase + tloc);
                    if (key < kv[i]) {
                        unsigned pos = atomicAdd(&cnt[tq4 + i], 1u);
                        if (pos < FCAP) { buf[tq4 + i][pos] = key; mask |= b; }
                    }
                }
            }
            __syncthreads();
            if (tid < QT) {
                unsigned n = cnt[tid];
                unsigned m = n < FCAP ? n : FCAP;
                for (unsigned e = 0; e < m; ++e) {
                    u64 key = buf[tid][e];
                    if (key < topk[tid][KNN - 1]) {
                        int p = KNN - 1;
                        while (p > 0 && topk[tid][p - 1] > key) {
                            topk[tid][p] = topk[tid][p - 1];
                            --p;
                        }
                        topk[tid][p] = key;
                    }
                }
                kth64[tid] = topk[tid][KNN - 1];
                if (n > FCAP) againF = 1;
                cnt[tid] = 0u;
            }
            __syncthreads();
            int go = againF;
            __syncthreads();
            if (tid == 0) againF = 0;
            if (!go) break;
            __syncthreads();
        }
    }

    __syncthreads();
    for (int i = tid; i < QT * KNN; i += 256) {
        int q = i >> 5, k = i & 31;
        cand[((size_t)(q0 + q) * NS + blockIdx.y) * KNN + k] = topk[q][k];
    }
}

__global__ void knn_merge(const u64* __restrict__ cand,
                          const int* __restrict__ y_train, int* __restrict__ out) {
    __shared__ u64 keys[NS * KNN];
    __shared__ u64 top[KNN];
    __shared__ int counts[NC];
    int q = blockIdx.x;
    for (int i = threadIdx.x; i < NS * KNN; i += 64)
        keys[i] = cand[(size_t)q * NS * KNN + i];
    for (int i = threadIdx.x; i < NC; i += 64) counts[i] = 0;
    if (threadIdx.x < KNN) top[threadIdx.x] = ~0ULL;
    __syncthreads();

    if (threadIdx.x == 0) {
        for (int s = 0; s < NS; ++s) {
            for (int j = 0; j < KNN; ++j) {
                u64 key = keys[s * KNN + j];
                if (key >= top[KNN - 1]) break;
                int p = KNN - 1;
                while (p > 0 && top[p - 1] > key) { top[p] = top[p - 1]; --p; }
                top[p] = key;
            }
        }
        for (int k = 0; k < KNN; ++k) {
            int idx = (int)(top[k] & 0xFFFF);
            counts[y_train[idx]]++;
        }
        int bestc = counts[0], bestl = 0;
        for (int c = 1; c < NC; ++c)
            if (counts[c] > bestc) { bestc = counts[c]; bestl = c; }
        out[q] = bestl;
    }
}

extern "C" void kernel_launch(void* const* d_in, const int* in_sizes, int n_in,
                              void* d_out, int out_size, void* d_ws, size_t ws_size,
                              hipStream_t stream) {
    const float* Xq = (const float*)d_in[0];   // [2048, 512]
    const float* Xt = (const float*)d_in[1];   // [65536, 512]
    const int*   y  = (const int*)d_in[2];     // [65536]
    int* out = (int*)d_out;                    // [2048] int32

    float* t2 = (float*)d_ws;                                   // 256 KB
    float* q2 = t2 + NT;                                        // 8 KB
    u64* cand = (u64*)(q2 + NQ);                                // 16.8 MB (fallback paths)
    u32* seed = (u32*)(cand + (size_t)NQ * NS * KNN);           // 8 KB
    u16* Qh = (u16*)(seed + NQ);                                // 2 MB
    u16* Ql = Qh + (size_t)NQ * DIM;                            // 2 MB
    u16* Th = Ql + (size_t)NQ * DIM;                            // 64 MB
    u16* Tl = Th + (size_t)NT * DIM;                            // 64 MB
    u64* glist = (u64*)(Tl + (size_t)NT * DIM);                 // 64 MB (filter path)
    u32* gcnt  = (u32*)(glist + (size_t)NQ * GCAP);             // 8 KB
    float* Dpre = (float*)glist;                                // 16 MB, aliases glist (dead before gemm)

    const size_t need = (size_t)(NT + NQ) * 4
                      + (size_t)NQ * NS * KNN * 8
                      + (size_t)NQ * 4
                      + 2 * ((size_t)NQ * DIM + (size_t)NT * DIM) * 2;  // ~148.3 MB
    const bool use_mfma = ws_size >= need;
    const bool use_filter = ws_size >= need + (size_t)NQ * GCAP * 8 + (size_t)NQ * 4;  // +64 MB

    norm_kernel<<<NT / 4, 256, 0, stream>>>(Xt, t2, NT);
    norm_kernel<<<NQ / 4, 256, 0, stream>>>(Xq, q2, NQ);
    if (use_mfma && use_filter) {
        split_kernel<<<(NQ * DIM / 4 + 255) / 256, 256, 0, stream>>>(Xq, Qh, Ql, NQ * DIM / 4);
        split_kernel<<<(NT * DIM / 4 + 255) / 256, 256, 0, stream>>>(Xt, Th, Tl, NT * DIM / 4);
        knn_pre<<<dim3(NQ / PQT, NTPRE / PSLICE), 256, 0, stream>>>(Xq, Xt, q2, t2, Dpre);
        seed_topk<<<NQ, 64, 0, stream>>>(Dpre, seed);
        hipMemsetAsync(gcnt, 0, NQ * sizeof(u32), stream);
        gemm_filter<<<dim3(NQ / 128, NT / 128), 256, 0, stream>>>(
            Qh, Ql, Th, Tl, q2, t2, seed, gcnt, glist);
        knn_topk<<<NQ, 64, 0, stream>>>(glist, gcnt, y, out);
    } else if (use_mfma) {
        hipMemsetAsync(seed, 0xFF, NQ * sizeof(u32), stream);
        split_kernel<<<(NQ * DIM / 4 + 255) / 256, 256, 0, stream>>>(Xq, Qh, Ql, NQ * DIM / 4);
        split_kernel<<<(NT * DIM / 4 + 255) / 256, 256, 0, stream>>>(Xt, Th, Tl, NT * DIM / 4);
        knn_prepass<<<dim3(NQ / PQT, NTPRE / PSLICE), 256, 0, stream>>>(Xq, Xt, q2, t2, seed);
        knn_mfma<<<dim3(NT / MSLICE, NQ / MQT), 512, 0, stream>>>(Qh, Ql, Th, Tl, q2, t2, seed, cand);
        knn_merge<<<NQ, 64, 0, stream>>>(cand, y, out);
    } else {
        knn_part<<<dim3(NQ / QT, NS), 256, 0, stream>>>(Xq, Xt, q2, t2, cand);
        knn_merge<<<NQ, 64, 0, stream>>>(cand, y, out);
    }
}